// Round 4
// baseline (153.888 us; speedup 1.0000x reference)
//
#include <hip/hip_runtime.h>
#include <hip/hip_bf16.h>
#include <stdint.h>

// Problem constants (B=16, N=512, D=768, H=6, Dh=128, layers=2)
#define BATCH 16
#define NSEQ  512
#define DMODEL 768
#define NHEAD 6
#define DHEAD 128
#define MROWS (BATCH * NSEQ)   // 8192
#define QBLK  32
#define KTILE 64

typedef __attribute__((ext_vector_type(8))) __bf16 bf16x8;
typedef __attribute__((ext_vector_type(4))) __bf16 bf16x4;
typedef __attribute__((ext_vector_type(4))) float  f32x4;
typedef __attribute__((ext_vector_type(4))) unsigned int u32x4;
typedef __attribute__((ext_vector_type(8))) unsigned short u16x8;

__device__ inline float fast_tanh(float x) {
    float ax = fabsf(x);
    float e  = __expf(-2.f * ax);
    float t  = (1.f - e) * __builtin_amdgcn_rcpf(1.f + e);
    return copysignf(t, x);
}

__device__ inline float b2f(unsigned short u) {
    union { unsigned int i; float f; } c;
    c.i = ((unsigned int)u) << 16;
    return c.f;
}

#define GLD16(gp, lp) __builtin_amdgcn_global_load_lds( \
    (const __attribute__((address_space(1))) unsigned int*)(gp), \
    (__attribute__((address_space(3))) unsigned int*)(lp), 16, 0, 0)

// ---------------- fp32 -> bf16 conversion (vectorized x4) ----------------
__global__ void cvt_bf16_kernel(const float* __restrict__ src,
                                __bf16* __restrict__ dst, int n4) {
    int i = blockIdx.x * blockDim.x + threadIdx.x;
    if (i < n4) {
        float4 v = reinterpret_cast<const float4*>(src)[i];
        bf16x4 o;
        o.x = (__bf16)v.x; o.y = (__bf16)v.y; o.z = (__bf16)v.z; o.w = (__bf16)v.w;
        reinterpret_cast<bf16x4*>(dst)[i] = o;
    }
}

// ---------------- bf16 MFMA GEMM + fused sq/sk epilogue -------------------
// C[m][n] = sum_k A[m][k] * Bm[n][k];  block bx covers cols of head h=bx.
// sq[h][row] = sum_d acc[row][h*128+d]*Wa[h][d], sk likewise (d+128).
// 2-phase prefetch double-buffer, 1 barrier/K-step, XCD-chunked grid.
__global__ __launch_bounds__(256) void gemm_bt(const __bf16* __restrict__ A,
                                               const __bf16* __restrict__ Bm,
                                               __bf16* __restrict__ C,
                                               const float* __restrict__ Wa,
                                               float* __restrict__ sq_t,
                                               float* __restrict__ sk_t) {
    __shared__ __bf16 As[2][128 * 32];
    __shared__ __bf16 Bs[2][128 * 32];
    const int tid  = threadIdx.x;
    const int lane = tid & 63;
    const int wave = tid >> 6;
    const int wm = wave >> 1, wn = wave & 1;

    // XCD-aware bijective swizzle: 384 = 8 * 48
    const int wg  = blockIdx.x;
    const int nid = (wg & 7) * 48 + (wg >> 3);
    const int bx  = nid % 6;          // head / n-panel
    const int by  = nid / 6;          // m-panel
    const int m0 = by * 128;
    const int n0 = bx * 128;

    f32x4 acc[4][4] = {};

    const int e0   = tid * 8;        // LDS elem offset; byte = tid*16 (lane-linear)
    const int row0 = tid >> 2;       // 0..63
    const int k0i  = (tid & 3) * 8;  // 0,8,16,24

    const int lr = lane & 15;
    const int lg = lane >> 4;
    const int kb = lg * 8;

    #define STAGE(kt, bufi) do { \
        GLD16(A  + (size_t)(m0 + row0)      * DMODEL + (kt) + k0i, &As[bufi][e0]); \
        GLD16(A  + (size_t)(m0 + row0 + 64) * DMODEL + (kt) + k0i, &As[bufi][e0 + 2048]); \
        GLD16(Bm + (size_t)(n0 + row0)      * DMODEL + (kt) + k0i, &Bs[bufi][e0]); \
        GLD16(Bm + (size_t)(n0 + row0 + 64) * DMODEL + (kt) + k0i, &Bs[bufi][e0 + 2048]); \
    } while (0)

    STAGE(0, 0);
    __syncthreads();

    for (int t = 0; t < 24; t++) {
        const int buf = t & 1;
        if (t < 23) STAGE((t + 1) * 32, buf ^ 1);   // prefetch next tile
        bf16x8 af[4], bfv[4];
        #pragma unroll
        for (int i = 0; i < 4; i++)
            af[i] = *reinterpret_cast<const bf16x8*>(&As[buf][(wm * 64 + i * 16 + lr) * 32 + kb]);
        #pragma unroll
        for (int j = 0; j < 4; j++)
            bfv[j] = *reinterpret_cast<const bf16x8*>(&Bs[buf][(wn * 64 + j * 16 + lr) * 32 + kb]);
        #pragma unroll
        for (int i = 0; i < 4; i++)
            #pragma unroll
            for (int j = 0; j < 4; j++)
                acc[i][j] = __builtin_amdgcn_mfma_f32_16x16x32_bf16(af[i], bfv[j], acc[i][j], 0, 0, 0);
        __syncthreads();   // drains prefetch vmcnt + protects buf swap
    }
    #undef STAGE

    // ---- C store (bf16) ----
    const int rg = lg * 4;
    #pragma unroll
    for (int i = 0; i < 4; i++) {
        #pragma unroll
        for (int j = 0; j < 4; j++) {
            #pragma unroll
            for (int r = 0; r < 4; r++) {
                int row = m0 + wm * 64 + i * 16 + rg + r;
                int col = n0 + wn * 64 + j * 16 + lr;
                C[(size_t)row * DMODEL + col] = (__bf16)acc[i][j][r];
            }
        }
    }

    // ---- fused sq/sk: reduce acc over this block's 128 cols (head bx) ----
    const int h = bx;
    float wqv[4], wkv[4];
    #pragma unroll
    for (int j = 0; j < 4; j++) {
        int d = wn * 64 + j * 16 + lr;
        wqv[j] = Wa[h * 256 + d];
        wkv[j] = Wa[h * 256 + 128 + d];
    }
    float* red = reinterpret_cast<float*>(&As[0][0]);   // reuse LDS: [2][128][2]
    #pragma unroll
    for (int i = 0; i < 4; i++) {
        #pragma unroll
        for (int r = 0; r < 4; r++) {
            float aq = 0.f, ak = 0.f;
            #pragma unroll
            for (int j = 0; j < 4; j++) {
                aq += acc[i][j][r] * wqv[j];
                ak += acc[i][j][r] * wkv[j];
            }
            #pragma unroll
            for (int off = 1; off < 16; off <<= 1) {
                aq += __shfl_xor(aq, off);
                ak += __shfl_xor(ak, off);
            }
            if (lr == 0) {
                int row = wm * 64 + i * 16 + rg + r;
                red[(0 * 128 + row) * 2 + wn] = aq;
                red[(1 * 128 + row) * 2 + wn] = ak;
            }
        }
    }
    __syncthreads();
    if (tid < 128) {
        sq_t[(size_t)h * MROWS + m0 + tid] = red[tid * 2] + red[tid * 2 + 1];
    } else {
        int row = tid - 128;
        sk_t[(size_t)h * MROWS + m0 + row] = red[(128 + row) * 2] + red[(128 + row) * 2 + 1];
    }
}

// ---------------- fused score/softmax/MFMA-PV/tanh/residual ----------------
// flat grid 1536, XCD-chunked decode; block 256 (4 waves).
__global__ __launch_bounds__(256) void attn_pv(const __bf16* __restrict__ QK,
                                               const float* __restrict__ sq_t,
                                               const float* __restrict__ sk_t,
                                               const float* __restrict__ pmask,
                                               const float* __restrict__ residual,
                                               float* __restrict__ out,
                                               __bf16* __restrict__ out_bf) {
    const int wg  = blockIdx.x;
    const int nid = (wg & 7) * 192 + (wg >> 3);   // bijective: 1536 = 8*192
    const int qt = nid & 15;
    const int hb = nid >> 4;     // 0..95
    const int h  = hb % NHEAD;
    const int b  = hb / NHEAD;
    const int q0 = qt * QBLK;

    __shared__ __bf16 w[QBLK][520];           // attn weights (numerator), bf16
    __shared__ __bf16 Vt[2][DHEAD][KTILE];    // transposed V, double-buffered, XOR-swizzled
    __shared__ float sks[NSEQ], pmk[NSEQ];
    __shared__ float sqs[QBLK], pmq[QBLK], rden[QBLK];
    const int tid  = threadIdx.x;
    const int lane = tid & 63;
    const int wave = tid >> 6;

    for (int k = tid; k < NSEQ; k += 256) {
        sks[k] = sk_t[(size_t)h * MROWS + b * NSEQ + k];
        pmk[k] = pmask[b * NSEQ + k];
    }
    if (tid < QBLK) {
        sqs[tid] = sq_t[(size_t)h * MROWS + b * NSEQ + q0 + tid];
        pmq[tid] = pmask[b * NSEQ + q0 + tid];
    }
    __syncthreads();

    // ---- phase 1: w[q][k] = exp(score); k-slice is g-invariant -> hoisted ----
    {
        const int k0 = (tid & 63) * 8;
        float4 ska = *reinterpret_cast<const float4*>(&sks[k0]);
        float4 skb = *reinterpret_cast<const float4*>(&sks[k0 + 4]);
        float4 pma = *reinterpret_cast<const float4*>(&pmk[k0]);
        float4 pmb = *reinterpret_cast<const float4*>(&pmk[k0 + 4]);
        float sarr[8] = {ska.x, ska.y, ska.z, ska.w, skb.x, skb.y, skb.z, skb.w};
        float parr[8] = {pma.x, pma.y, pma.z, pma.w, pmb.x, pmb.y, pmb.z, pmb.w};
        #pragma unroll
        for (int g = 0; g < 8; g++) {
            int q = (tid >> 6) + g * 4;
            float sqv = sqs[q], pq = pmq[q];
            bf16x8 wv;
            #pragma unroll
            for (int j = 0; j < 8; j++) {
                float s = (pq * parr[j] > 0.f) ? fast_tanh(sqv + sarr[j]) : -1e-8f;
                wv[j] = (__bf16)__expf(s);
            }
            *reinterpret_cast<bf16x8*>(&w[q][k0]) = wv;
        }
    }
    __syncthreads();

    // ---- row sums -> rden ----
    {
        int row = tid >> 3, c = tid & 7;
        float p = 0.f;
        #pragma unroll
        for (int j = 0; j < 8; j++) {
            bf16x8 v = *reinterpret_cast<const bf16x8*>(&w[row][c * 8 + j * 64]);
            #pragma unroll
            for (int e = 0; e < 8; e++) p += (float)v[e];
        }
        #pragma unroll
        for (int off = 4; off; off >>= 1) p += __shfl_down(p, off);
        if (c == 0) rden[row] = 1.f / p;
    }

    // ---- phase 2: PV via MFMA, 8 tiles of KTILE=64, double-buffered Vt ----
    const int sd0 = (tid & 15) * 8;
    const int sk0 = (tid >> 4) * 4;     // 0..60
    const __bf16* Vbase = QK + (size_t)b * NSEQ * DMODEL + (size_t)h * DHEAD + sd0;

    u16x8 r0, r1, r2, r3;
    #define LOADS(t) do { \
        const __bf16* p = Vbase + (size_t)((t) * KTILE + sk0) * DMODEL; \
        r0 = *reinterpret_cast<const u16x8*>(p); \
        r1 = *reinterpret_cast<const u16x8*>(p + DMODEL); \
        r2 = *reinterpret_cast<const u16x8*>(p + 2 * DMODEL); \
        r3 = *reinterpret_cast<const u16x8*>(p + 3 * DMODEL); \
    } while (0)

    #define WRITEV(bufi) do { \
        _Pragma("unroll") \
        for (int j = 0; j < 8; j++) { \
            int d = sd0 + j; \
            int swz = j ^ (tid & 7); \
            unsigned long long pk = (unsigned long long)r0[j] \
                                  | ((unsigned long long)r1[j] << 16) \
                                  | ((unsigned long long)r2[j] << 32) \
                                  | ((unsigned long long)r3[j] << 48); \
            *reinterpret_cast<unsigned long long*>( \
                reinterpret_cast<char*>(&Vt[bufi][0][0]) + d * (KTILE * 2) + ((sk0 ^ (swz << 3)) * 2)) = pk; \
        } \
    } while (0)

    const int wq0 = (wave & 1) * 16;
    const int wd0 = (wave >> 1) * 64;
    const int lr  = lane & 15;
    const int lg  = lane >> 4;

    f32x4 acc[4] = {};

    LOADS(0);
    WRITEV(0);
    LOADS(1);
    __syncthreads();

    for (int t = 0; t < 8; t++) {
        const int buf = t & 1;
        #pragma unroll
        for (int ks = 0; ks < 2; ks++) {
            bf16x8 af = *reinterpret_cast<const bf16x8*>(&w[wq0 + lr][t * 64 + ks * 32 + lg * 8]);
            #pragma unroll
            for (int n = 0; n < 4; n++) {
                int d   = wd0 + n * 16 + lr;
                int kbk = ks * 4 + lg;
                int swz = (d & 7) ^ ((d >> 3) & 7);
                bf16x8 bv = *reinterpret_cast<const bf16x8*>(
                    reinterpret_cast<const char*>(&Vt[buf][0][0]) + d * (KTILE * 2) + ((kbk ^ swz) * 16));
                acc[n] = __builtin_amdgcn_mfma_f32_16x16x32_bf16(af, bv, acc[n], 0, 0, 0);
            }
        }
        if (t < 7) WRITEV(buf ^ 1);   // stage tile t+1
        if (t < 6) LOADS(t + 2);      // issue next loads under next MFMA phase
        __syncthreads();
    }

    // ---- epilogue: normalize, tanh, +residual (+optional bf16 copy) ----
    #pragma unroll
    for (int n = 0; n < 4; n++) {
        #pragma unroll
        for (int r = 0; r < 4; r++) {
            int ql = wq0 + lg * 4 + r;
            int d  = wd0 + n * 16 + lr;
            float hv = acc[n][r] * rden[ql];
            float tv = fast_tanh(hv);
            size_t o = ((size_t)(b * NSEQ + q0 + ql)) * DMODEL + (size_t)h * DHEAD + d;
            float ov = residual[o] + tv;
            out[o] = ov;
            if (out_bf) out_bf[o] = (__bf16)ov;
        }
    }
    #undef LOADS
    #undef WRITEV
}

extern "C" void kernel_launch(void* const* d_in, const int* in_sizes, int n_in,
                              void* d_out, int out_size, void* d_ws, size_t ws_size,
                              hipStream_t stream) {
    const float* pmask   = (const float*)d_in[0];
    const float* feature = (const float*)d_in[1];
    const float* W       = (const float*)d_in[2];
    const float* Wa      = (const float*)d_in[3];
    float* out = (float*)d_out;
    char* ws = (char*)d_ws;

    __bf16* Abf  = (__bf16*)ws;
    __bf16* Wbf  = (__bf16*)(ws + 12582912);
    __bf16* QKbf = (__bf16*)(ws + 12582912 + 1179648);
    float*  sq   = (float*)(ws + 12582912 + 1179648 + 12582912);
    float*  sk   = sq + MROWS * NHEAD;

    const int featN4 = (MROWS * DMODEL) / 4;
    const int wN4    = (DMODEL * DMODEL) / 4;

    hipLaunchKernelGGL(cvt_bf16_kernel, dim3((wN4 + 255) / 256), dim3(256), 0, stream,
                       W, Wbf, wN4);

    // ---- layer 1 ----
    hipLaunchKernelGGL(cvt_bf16_kernel, dim3((featN4 + 255) / 256), dim3(256), 0, stream,
                       feature, Abf, featN4);
    hipLaunchKernelGGL(gemm_bt, dim3(384), dim3(256), 0, stream,
                       Abf, Wbf, QKbf, Wa, sq, sk);
    hipLaunchKernelGGL(attn_pv, dim3(1536), dim3(256), 0, stream,
                       QKbf, sq, sk, pmask, feature, out, Abf);   // writes bf16 out too

    // ---- layer 2 ----
    hipLaunchKernelGGL(gemm_bt, dim3(384), dim3(256), 0, stream,
                       Abf, Wbf, QKbf, Wa, sq, sk);
    hipLaunchKernelGGL(attn_pv, dim3(1536), dim3(256), 0, stream,
                       QKbf, sq, sk, pmask, out, out, (__bf16*)nullptr);
}

// Round 5
// 142.375 us; speedup vs baseline: 1.0809x; 1.0809x over previous
//
#include <hip/hip_runtime.h>
#include <hip/hip_bf16.h>
#include <stdint.h>

// Problem constants (B=16, N=512, D=768, H=6, Dh=128, layers=2)
#define BATCH 16
#define NSEQ  512
#define DMODEL 768
#define NHEAD 6
#define DHEAD 128
#define MROWS (BATCH * NSEQ)   // 8192
#define QBLK  32
#define KTILE 64

typedef __attribute__((ext_vector_type(8))) __bf16 bf16x8;
typedef __attribute__((ext_vector_type(4))) __bf16 bf16x4;
typedef __attribute__((ext_vector_type(4))) float  f32x4;
typedef __attribute__((ext_vector_type(8))) unsigned short u16x8;

#define GLD16(gp, lp) __builtin_amdgcn_global_load_lds( \
    (const __attribute__((address_space(1))) unsigned int*)(gp), \
    (__attribute__((address_space(3))) unsigned int*)(lp), 16, 0, 0)

// raw barrier (does NOT drain vmcnt -> global loads stay in flight)
#define BAR_PLAIN() do { asm volatile("" ::: "memory"); \
    __builtin_amdgcn_s_barrier(); asm volatile("" ::: "memory"); } while (0)
// barrier with LDS-write flush (producer side of ds_write -> cross-wave read)
#define BAR_LGKM() do { asm volatile("s_waitcnt lgkmcnt(0)" ::: "memory"); \
    __builtin_amdgcn_s_barrier(); asm volatile("" ::: "memory"); } while (0)

// ---------------- fp32 -> bf16 conversion (vectorized x4) ----------------
__global__ void cvt_bf16_kernel(const float* __restrict__ src,
                                __bf16* __restrict__ dst, int n4) {
    int i = blockIdx.x * blockDim.x + threadIdx.x;
    if (i < n4) {
        float4 v = reinterpret_cast<const float4*>(src)[i];
        bf16x4 o;
        o.x = (__bf16)v.x; o.y = (__bf16)v.y; o.z = (__bf16)v.z; o.w = (__bf16)v.w;
        reinterpret_cast<bf16x4*>(dst)[i] = o;
    }
}

// ---------------- bf16 MFMA GEMM (64x128 tile) + fused sq/sk epilogue -----
// C[m][n] = sum_k A[m][k]*Bm[n][k]; block covers 64 m-rows x 128 n-cols
// (one full head h = bx). grid 768 = 3 blocks/CU. Counted-vmcnt pipeline.
__global__ __launch_bounds__(256) void gemm_bt(const __bf16* __restrict__ A,
                                               const __bf16* __restrict__ Bm,
                                               __bf16* __restrict__ C,
                                               const float* __restrict__ Wa,
                                               float* __restrict__ sq_t,
                                               float* __restrict__ sk_t) {
    __shared__ __align__(16) __bf16 As[2][64 * 32];    // 4 KB each
    __shared__ __align__(16) __bf16 Bs[2][128 * 32];   // 8 KB each
    const int tid  = threadIdx.x;
    const int lane = tid & 63;
    const int wave = tid >> 6;
    const int wm = wave >> 1, wn = wave & 1;   // wave: 32m x 64n

    // XCD-aware bijective swizzle: 768 = 8 * 96
    const int wg  = blockIdx.x;
    const int nid = (wg & 7) * 96 + (wg >> 3);
    const int bx  = nid % 6;          // head / n-panel (128 cols)
    const int by  = nid / 6;          // m-panel (64 rows)
    const int m0 = by * 64;
    const int n0 = bx * 128;

    f32x4 acc[2][4] = {};

    const int e0   = tid * 8;        // LDS elem offset (byte = tid*16, lane-linear)
    const int row0 = tid >> 2;       // 0..63
    const int k0i  = (tid & 3) * 8;

    const int lr = lane & 15;
    const int lg = lane >> 4;
    const int kb = lg * 8;

    #define STAGE(kt, bufi) do { \
        GLD16(A  + (size_t)(m0 + row0)      * DMODEL + (kt) + k0i, &As[bufi][e0]); \
        GLD16(Bm + (size_t)(n0 + row0)      * DMODEL + (kt) + k0i, &Bs[bufi][e0]); \
        GLD16(Bm + (size_t)(n0 + row0 + 64) * DMODEL + (kt) + k0i, &Bs[bufi][e0 + 2048]); \
    } while (0)

    STAGE(0, 0);

    for (int t = 0; t < 24; t++) {
        const int buf = t & 1;
        if (t < 23) {
            STAGE((t + 1) * 32, buf ^ 1);                     // keep 1 tile in flight
            asm volatile("s_waitcnt vmcnt(3)" ::: "memory");  // wait tile t only
        } else {
            asm volatile("s_waitcnt vmcnt(0)" ::: "memory");
        }
        __builtin_amdgcn_s_barrier();                          // tile t visible to all
        asm volatile("" ::: "memory");

        bf16x8 af[2], bfv[4];
        #pragma unroll
        for (int i = 0; i < 2; i++)
            af[i] = *reinterpret_cast<const bf16x8*>(&As[buf][(wm * 32 + i * 16 + lr) * 32 + kb]);
        #pragma unroll
        for (int j = 0; j < 4; j++)
            bfv[j] = *reinterpret_cast<const bf16x8*>(&Bs[buf][(wn * 64 + j * 16 + lr) * 32 + kb]);
        #pragma unroll
        for (int i = 0; i < 2; i++)
            #pragma unroll
            for (int j = 0; j < 4; j++)
                acc[i][j] = __builtin_amdgcn_mfma_f32_16x16x32_bf16(af[i], bfv[j], acc[i][j], 0, 0, 0);

        BAR_PLAIN();   // reads of buf done before next-iter STAGE overwrites buf^1->buf
    }
    #undef STAGE

    // ---- C store (bf16) ----
    const int rg = lg * 4;
    #pragma unroll
    for (int i = 0; i < 2; i++) {
        #pragma unroll
        for (int j = 0; j < 4; j++) {
            #pragma unroll
            for (int r = 0; r < 4; r++) {
                int row = m0 + wm * 32 + i * 16 + rg + r;
                int col = n0 + wn * 64 + j * 16 + lr;
                C[(size_t)row * DMODEL + col] = (__bf16)acc[i][j][r];
            }
        }
    }

    // ---- fused sq/sk: reduce acc over this head's 128 cols ----
    const int h = bx;
    float wqv[4], wkv[4];
    #pragma unroll
    for (int j = 0; j < 4; j++) {
        int d = wn * 64 + j * 16 + lr;
        wqv[j] = Wa[h * 256 + d];
        wkv[j] = Wa[h * 256 + 128 + d];
    }
    float* red = reinterpret_cast<float*>(&As[0][0]);   // 1 KB scratch: [2][64][2]
    #pragma unroll
    for (int i = 0; i < 2; i++) {
        #pragma unroll
        for (int r = 0; r < 4; r++) {
            float aq = 0.f, ak = 0.f;
            #pragma unroll
            for (int j = 0; j < 4; j++) {
                aq += acc[i][j][r] * wqv[j];
                ak += acc[i][j][r] * wkv[j];
            }
            #pragma unroll
            for (int off = 1; off < 16; off <<= 1) {
                aq += __shfl_xor(aq, off);
                ak += __shfl_xor(ak, off);
            }
            if (lr == 0) {
                int row = wm * 32 + i * 16 + rg + r;
                red[(0 * 64 + row) * 2 + wn] = aq;
                red[(1 * 64 + row) * 2 + wn] = ak;
            }
        }
    }
    __syncthreads();
    if (tid < 64) {
        sq_t[(size_t)h * MROWS + m0 + tid] = red[tid * 2] + red[tid * 2 + 1];
    } else if (tid < 128) {
        int row = tid - 64;
        sk_t[(size_t)h * MROWS + m0 + row] = red[(64 + row) * 2] + red[(64 + row) * 2 + 1];
    }
}

// ---------------- fused score/softmax/MFMA-PV/tanh/residual ----------------
// flat grid 1536 XCD-chunked; block 256 (4 waves). LDS ~52.9KB -> 3 blocks/CU.
__global__ __launch_bounds__(256) void attn_pv(const __bf16* __restrict__ QK,
                                               const float* __restrict__ sq_t,
                                               const float* __restrict__ sk_t,
                                               const float* __restrict__ pmask,
                                               const float* __restrict__ residual,
                                               float* __restrict__ out,
                                               __bf16* __restrict__ out_bf) {
    const int wg  = blockIdx.x;
    const int nid = (wg & 7) * 192 + (wg >> 3);   // bijective: 1536 = 8*192
    const int qt = nid & 15;
    const int hb = nid >> 4;
    const int h  = hb % NHEAD;
    const int b  = hb / NHEAD;
    const int q0 = qt * QBLK;

    __shared__ __align__(16) __bf16 w[QBLK][520];        // 33,280 B
    __shared__ __align__(16) __bf16 Vt[DHEAD * KTILE];   // 16,384 B (single buf, swizzled)
    __shared__ __align__(16) float eks[NSEQ];            // e^{2 sk}
    __shared__ __align__(16) float pmk[NSEQ];
    __shared__ float eqs[QBLK], pmq[QBLK], rden[QBLK];
    const int tid  = threadIdx.x;
    const int lane = tid & 63;
    const int wave = tid >> 6;

    for (int k = tid; k < NSEQ; k += 256) {
        eks[k] = __expf(2.f * sk_t[(size_t)h * MROWS + b * NSEQ + k]);
        pmk[k] = pmask[b * NSEQ + k];
    }
    if (tid < QBLK) {
        eqs[tid] = __expf(2.f * sq_t[(size_t)h * MROWS + b * NSEQ + q0 + tid]);
        pmq[tid] = pmask[b * NSEQ + q0 + tid];
    }
    __syncthreads();

    // ---- phase 1: w[q][k] = exp(tanh(sq+sk)) via u = eq*ek; fused row-sums ----
    {
        const int k0 = lane * 8;
        float4 ea = *reinterpret_cast<const float4*>(&eks[k0]);
        float4 eb = *reinterpret_cast<const float4*>(&eks[k0 + 4]);
        float4 pa = *reinterpret_cast<const float4*>(&pmk[k0]);
        float4 pb = *reinterpret_cast<const float4*>(&pmk[k0 + 4]);
        float earr[8] = {ea.x, ea.y, ea.z, ea.w, eb.x, eb.y, eb.z, eb.w};
        float parr[8] = {pa.x, pa.y, pa.z, pa.w, pb.x, pb.y, pb.z, pb.w};
        #pragma unroll
        for (int g = 0; g < 8; g++) {
            int q = wave + g * 4;          // all lanes in wave share q
            float eqv = eqs[q], pq = pmq[q];
            float psum = 0.f;
            bf16x8 wv;
            #pragma unroll
            for (int j = 0; j < 8; j++) {
                float u  = eqv * earr[j];
                float tt = 1.f - 2.f * __builtin_amdgcn_rcpf(u + 1.f);  // tanh
                float s  = (pq * parr[j] > 0.f) ? tt : -1e-8f;
                float wf = __expf(s);
                psum += wf;
                wv[j] = (__bf16)wf;
            }
            *reinterpret_cast<bf16x8*>(&w[q][k0]) = wv;
            #pragma unroll
            for (int off = 1; off < 64; off <<= 1) psum += __shfl_xor(psum, off);
            if (lane == 0) rden[q] = __builtin_amdgcn_rcpf(psum);
        }
    }
    __syncthreads();

    // ---- phase 2: PV via MFMA, 8 tiles of KTILE=64, single Vt + 2 reg sets ----
    const int sd0 = (tid & 15) * 8;
    const int sk0 = (tid >> 4) * 4;     // 0..60
    const __bf16* Vbase = QK + (size_t)b * NSEQ * DMODEL + (size_t)h * DHEAD + sd0;
    char* vtb = reinterpret_cast<char*>(&Vt[0]);

    u16x8 A0, A1, A2, A3, B0, B1, B2, B3;
    #define LOADS(S0, S1, S2, S3, t) do { \
        const __bf16* p = Vbase + (size_t)((t) * KTILE + sk0) * DMODEL; \
        S0 = *reinterpret_cast<const u16x8*>(p); \
        S1 = *reinterpret_cast<const u16x8*>(p + DMODEL); \
        S2 = *reinterpret_cast<const u16x8*>(p + 2 * DMODEL); \
        S3 = *reinterpret_cast<const u16x8*>(p + 3 * DMODEL); \
    } while (0)

    // Vt[d][kc']: kc' = kc ^ (8*swz(d)), swz(d) = (d&7)^((d>>3)&7); conflict-free
    #define WRITEV(S0, S1, S2, S3) do { \
        _Pragma("unroll") \
        for (int j = 0; j < 8; j++) { \
            int d = sd0 + j; \
            int swz = j ^ (tid & 7); \
            unsigned long long pk = (unsigned long long)(unsigned short)S0[j] \
                                  | ((unsigned long long)(unsigned short)S1[j] << 16) \
                                  | ((unsigned long long)(unsigned short)S2[j] << 32) \
                                  | ((unsigned long long)(unsigned short)S3[j] << 48); \
            *reinterpret_cast<unsigned long long*>(vtb + d * 128 + ((sk0 ^ (swz << 3)) * 2)) = pk; \
        } \
    } while (0)

    const int wq0 = (wave & 1) * 16;
    const int wd0 = (wave >> 1) * 64;
    const int lr  = lane & 15;
    const int lg  = lane >> 4;

    f32x4 acc[4] = {};

    LOADS(A0, A1, A2, A3, 0);
    LOADS(B0, B1, B2, B3, 1);
    WRITEV(A0, A1, A2, A3);            // tile 0 into Vt
    LOADS(A0, A1, A2, A3, 2);          // set A now carries tile 2
    BAR_LGKM();

    #pragma unroll
    for (int t = 0; t < 8; t++) {
        // MFMA on tile t (currently in Vt)
        #pragma unroll
        for (int ks = 0; ks < 2; ks++) {
            bf16x8 af = *reinterpret_cast<const bf16x8*>(&w[wq0 + lr][t * 64 + ks * 32 + lg * 8]);
            #pragma unroll
            for (int n = 0; n < 4; n++) {
                int d    = wd0 + n * 16 + lr;
                int kbk  = ks * 4 + lg;
                int swzd = (d & 7) ^ ((d >> 3) & 7);
                bf16x8 bv = *reinterpret_cast<const bf16x8*>(vtb + d * 128 + ((kbk ^ swzd) << 4));
                acc[n] = __builtin_amdgcn_mfma_f32_16x16x32_bf16(af, bv, acc[n], 0, 0, 0);
            }
        }
        BAR_PLAIN();                   // all waves done reading tile t
        if (t < 7) {
            if ((t & 1) == 0) WRITEV(B0, B1, B2, B3);   // tile t+1 (odd -> set B)
            else              WRITEV(A0, A1, A2, A3);   // tile t+1 (even -> set A)
        }
        if (t < 5) {
            if ((t & 1) == 0) LOADS(B0, B1, B2, B3, t + 3);
            else              LOADS(A0, A1, A2, A3, t + 3);
        }
        BAR_LGKM();                    // tile t+1 visible; global loads stay in flight
    }

    // ---- epilogue: normalize, tanh, +residual (+optional bf16 copy) ----
    #pragma unroll
    for (int n = 0; n < 4; n++) {
        #pragma unroll
        for (int r = 0; r < 4; r++) {
            int ql = wq0 + lg * 4 + r;
            int d  = wd0 + n * 16 + lr;
            float hv = acc[n][r] * rden[ql];
            float e2 = __expf(2.f * hv);
            float tv = 1.f - 2.f * __builtin_amdgcn_rcpf(e2 + 1.f);   // tanh(hv)
            size_t o = ((size_t)(b * NSEQ + q0 + ql)) * DMODEL + (size_t)h * DHEAD + d;
            float ov = residual[o] + tv;
            out[o] = ov;
            if (out_bf) out_bf[o] = (__bf16)ov;
        }
    }
    #undef LOADS
    #undef WRITEV
}

extern "C" void kernel_launch(void* const* d_in, const int* in_sizes, int n_in,
                              void* d_out, int out_size, void* d_ws, size_t ws_size,
                              hipStream_t stream) {
    const float* pmask   = (const float*)d_in[0];
    const float* feature = (const float*)d_in[1];
    const float* W       = (const float*)d_in[2];
    const float* Wa      = (const float*)d_in[3];
    float* out = (float*)d_out;
    char* ws = (char*)d_ws;

    __bf16* Abf  = (__bf16*)ws;
    __bf16* Wbf  = (__bf16*)(ws + 12582912);
    __bf16* QKbf = (__bf16*)(ws + 12582912 + 1179648);
    float*  sq   = (float*)(ws + 12582912 + 1179648 + 12582912);
    float*  sk   = sq + MROWS * NHEAD;

    const int featN4 = (MROWS * DMODEL) / 4;
    const int wN4    = (DMODEL * DMODEL) / 4;

    hipLaunchKernelGGL(cvt_bf16_kernel, dim3((wN4 + 255) / 256), dim3(256), 0, stream,
                       W, Wbf, wN4);

    // ---- layer 1 ----
    hipLaunchKernelGGL(cvt_bf16_kernel, dim3((featN4 + 255) / 256), dim3(256), 0, stream,
                       feature, Abf, featN4);
    hipLaunchKernelGGL(gemm_bt, dim3(768), dim3(256), 0, stream,
                       Abf, Wbf, QKbf, Wa, sq, sk);
    hipLaunchKernelGGL(attn_pv, dim3(1536), dim3(256), 0, stream,
                       QKbf, sq, sk, pmask, feature, out, Abf);   // also writes bf16 out

    // ---- layer 2 ----
    hipLaunchKernelGGL(gemm_bt, dim3(768), dim3(256), 0, stream,
                       Abf, Wbf, QKbf, Wa, sq, sk);
    hipLaunchKernelGGL(attn_pv, dim3(1536), dim3(256), 0, stream,
                       QKbf, sq, sk, pmask, out, out, (__bf16*)nullptr);
}

// Round 6
// 139.916 us; speedup vs baseline: 1.0999x; 1.0176x over previous
//
#include <hip/hip_runtime.h>
#include <hip/hip_bf16.h>
#include <stdint.h>

// Problem constants (B=16, N=512, D=768, H=6, Dh=128, layers=2)
#define BATCH 16
#define NSEQ  512
#define DMODEL 768
#define NHEAD 6
#define DHEAD 128
#define MROWS (BATCH * NSEQ)   // 8192
#define QBLK  16
#define KTILE 64

typedef __attribute__((ext_vector_type(8))) __bf16 bf16x8;
typedef __attribute__((ext_vector_type(4))) __bf16 bf16x4;
typedef __attribute__((ext_vector_type(4))) float  f32x4;
typedef __attribute__((ext_vector_type(8))) unsigned short u16x8;

#define GLD16(gp, lp) __builtin_amdgcn_global_load_lds( \
    (const __attribute__((address_space(1))) unsigned int*)(gp), \
    (__attribute__((address_space(3))) unsigned int*)(lp), 16, 0, 0)

// raw barrier (does NOT drain vmcnt -> global loads stay in flight)
#define BAR_PLAIN() do { asm volatile("" ::: "memory"); \
    __builtin_amdgcn_s_barrier(); asm volatile("" ::: "memory"); } while (0)
// barrier with LDS-op flush (producer side of ds_write -> cross-wave read)
#define BAR_LGKM() do { asm volatile("s_waitcnt lgkmcnt(0)" ::: "memory"); \
    __builtin_amdgcn_s_barrier(); asm volatile("" ::: "memory"); } while (0)

// degree-6 Taylor exp(t) for t in [-1,1]; rel err <5e-4 (below bf16 rounding)
__device__ inline float poly_exp6(float t) {
    float p = 1.38888889e-3f;            // 1/720
    p = fmaf(p, t, 8.33333333e-3f);      // 1/120
    p = fmaf(p, t, 4.16666667e-2f);      // 1/24
    p = fmaf(p, t, 1.66666667e-1f);      // 1/6
    p = fmaf(p, t, 0.5f);
    p = fmaf(p, t, 1.0f);
    p = fmaf(p, t, 1.0f);
    return p;
}

// ---------------- fp32 -> bf16 conversion (vectorized x4) ----------------
__global__ void cvt_bf16_kernel(const float* __restrict__ src,
                                __bf16* __restrict__ dst, int n4) {
    int i = blockIdx.x * blockDim.x + threadIdx.x;
    if (i < n4) {
        float4 v = reinterpret_cast<const float4*>(src)[i];
        bf16x4 o;
        o.x = (__bf16)v.x; o.y = (__bf16)v.y; o.z = (__bf16)v.z; o.w = (__bf16)v.w;
        reinterpret_cast<bf16x4*>(dst)[i] = o;
    }
}

// ---------------- bf16 MFMA GEMM (64x128 tile) + fused sq/sk epilogue -----
__global__ __launch_bounds__(256) void gemm_bt(const __bf16* __restrict__ A,
                                               const __bf16* __restrict__ Bm,
                                               __bf16* __restrict__ C,
                                               const float* __restrict__ Wa,
                                               float* __restrict__ sq_t,
                                               float* __restrict__ sk_t) {
    __shared__ __align__(16) __bf16 As[2][64 * 32];
    __shared__ __align__(16) __bf16 Bs[2][128 * 32];
    const int tid  = threadIdx.x;
    const int lane = tid & 63;
    const int wave = tid >> 6;
    const int wm = wave >> 1, wn = wave & 1;   // wave: 32m x 64n

    const int wg  = blockIdx.x;
    const int nid = (wg & 7) * 96 + (wg >> 3);  // 768 = 8*96
    const int bx  = nid % 6;
    const int by  = nid / 6;
    const int m0 = by * 64;
    const int n0 = bx * 128;

    f32x4 acc[2][4] = {};

    const int e0   = tid * 8;
    const int row0 = tid >> 2;
    const int k0i  = (tid & 3) * 8;

    const int lr = lane & 15;
    const int lg = lane >> 4;
    const int kb = lg * 8;

    #define STAGE(kt, bufi) do { \
        GLD16(A  + (size_t)(m0 + row0)      * DMODEL + (kt) + k0i, &As[bufi][e0]); \
        GLD16(Bm + (size_t)(n0 + row0)      * DMODEL + (kt) + k0i, &Bs[bufi][e0]); \
        GLD16(Bm + (size_t)(n0 + row0 + 64) * DMODEL + (kt) + k0i, &Bs[bufi][e0 + 2048]); \
    } while (0)

    STAGE(0, 0);

    for (int t = 0; t < 24; t++) {
        const int buf = t & 1;
        if (t < 23) {
            STAGE((t + 1) * 32, buf ^ 1);
            asm volatile("s_waitcnt vmcnt(3)" ::: "memory");
        } else {
            asm volatile("s_waitcnt vmcnt(0)" ::: "memory");
        }
        __builtin_amdgcn_s_barrier();
        asm volatile("" ::: "memory");

        bf16x8 af[2], bfv[4];
        #pragma unroll
        for (int i = 0; i < 2; i++)
            af[i] = *reinterpret_cast<const bf16x8*>(&As[buf][(wm * 32 + i * 16 + lr) * 32 + kb]);
        #pragma unroll
        for (int j = 0; j < 4; j++)
            bfv[j] = *reinterpret_cast<const bf16x8*>(&Bs[buf][(wn * 64 + j * 16 + lr) * 32 + kb]);
        #pragma unroll
        for (int i = 0; i < 2; i++)
            #pragma unroll
            for (int j = 0; j < 4; j++)
                acc[i][j] = __builtin_amdgcn_mfma_f32_16x16x32_bf16(af[i], bfv[j], acc[i][j], 0, 0, 0);

        BAR_PLAIN();
    }
    #undef STAGE

    const int rg = lg * 4;
    #pragma unroll
    for (int i = 0; i < 2; i++) {
        #pragma unroll
        for (int j = 0; j < 4; j++) {
            #pragma unroll
            for (int r = 0; r < 4; r++) {
                int row = m0 + wm * 32 + i * 16 + rg + r;
                int col = n0 + wn * 64 + j * 16 + lr;
                C[(size_t)row * DMODEL + col] = (__bf16)acc[i][j][r];
            }
        }
    }

    // ---- fused sq/sk ----
    const int h = bx;
    float wqv[4], wkv[4];
    #pragma unroll
    for (int j = 0; j < 4; j++) {
        int d = wn * 64 + j * 16 + lr;
        wqv[j] = Wa[h * 256 + d];
        wkv[j] = Wa[h * 256 + 128 + d];
    }
    float* red = reinterpret_cast<float*>(&As[0][0]);
    #pragma unroll
    for (int i = 0; i < 2; i++) {
        #pragma unroll
        for (int r = 0; r < 4; r++) {
            float aq = 0.f, ak = 0.f;
            #pragma unroll
            for (int j = 0; j < 4; j++) {
                aq += acc[i][j][r] * wqv[j];
                ak += acc[i][j][r] * wkv[j];
            }
            #pragma unroll
            for (int off = 1; off < 16; off <<= 1) {
                aq += __shfl_xor(aq, off);
                ak += __shfl_xor(ak, off);
            }
            if (lr == 0) {
                int row = wm * 32 + i * 16 + rg + r;
                red[(0 * 64 + row) * 2 + wn] = aq;
                red[(1 * 64 + row) * 2 + wn] = ak;
            }
        }
    }
    __syncthreads();
    if (tid < 64) {
        sq_t[(size_t)h * MROWS + m0 + tid] = red[tid * 2] + red[tid * 2 + 1];
    } else if (tid < 128) {
        int row = tid - 64;
        sk_t[(size_t)h * MROWS + m0 + row] = red[(64 + row) * 2] + red[(64 + row) * 2 + 1];
    }
}

// ---------------- fused score/softmax/MFMA-PV/tanh/residual ----------------
// grid 3072 XCD-chunked; block 256 (4 waves). LDS exactly 32,768 B.
// Each wave: all 16 q-rows x 32 d-cols (wd0 = wave*32). Row-sums via ones-MFMA.
__global__ __launch_bounds__(256) void attn_pv(const __bf16* __restrict__ QK,
                                               const float* __restrict__ sq_t,
                                               const float* __restrict__ sk_t,
                                               const float* __restrict__ pmask,
                                               const float* __restrict__ residual,
                                               float* __restrict__ out,
                                               __bf16* __restrict__ out_bf) {
    const int wg  = blockIdx.x;
    const int nid = (wg & 7) * 384 + (wg >> 3);   // bijective: 3072 = 8*384
    const int qt = nid & 31;          // 32 q-tiles of 16
    const int hb = nid >> 5;          // 0..95
    const int h  = hb % NHEAD;
    const int b  = hb / NHEAD;
    const int q0 = qt * QBLK;

    __shared__ __align__(16) __bf16 w[QBLK][512];        // 16,384 B
    __shared__ __align__(16) __bf16 Vt[DHEAD * KTILE];   // 16,384 B
    const int tid  = threadIdx.x;
    const int lane = tid & 63;
    const int wave = tid >> 6;

    // ---- phase 2 staging geometry; issue V tiles 0,1 EARLY ----
    const int sd0 = (tid & 15) * 8;
    const int sk0 = (tid >> 4) * 4;
    const __bf16* Vbase = QK + (size_t)b * NSEQ * DMODEL + (size_t)h * DHEAD + sd0;
    char* vtb = reinterpret_cast<char*>(&Vt[0]);

    u16x8 A0, A1, A2, A3, B0, B1, B2, B3;
    #define LOADS(S0, S1, S2, S3, t) do { \
        const __bf16* p = Vbase + (size_t)((t) * KTILE + sk0) * DMODEL; \
        S0 = *reinterpret_cast<const u16x8*>(p); \
        S1 = *reinterpret_cast<const u16x8*>(p + DMODEL); \
        S2 = *reinterpret_cast<const u16x8*>(p + 2 * DMODEL); \
        S3 = *reinterpret_cast<const u16x8*>(p + 3 * DMODEL); \
    } while (0)
    #define WRITEV(S0, S1, S2, S3) do { \
        _Pragma("unroll") \
        for (int j = 0; j < 8; j++) { \
            int d = sd0 + j; \
            int swz = j ^ (tid & 7); \
            unsigned long long pk = (unsigned long long)(unsigned short)S0[j] \
                                  | ((unsigned long long)(unsigned short)S1[j] << 16) \
                                  | ((unsigned long long)(unsigned short)S2[j] << 32) \
                                  | ((unsigned long long)(unsigned short)S3[j] << 48); \
            *reinterpret_cast<unsigned long long*>(vtb + d * 128 + ((sk0 ^ (swz << 3)) * 2)) = pk; \
        } \
    } while (0)

    LOADS(A0, A1, A2, A3, 0);          // latency hidden under phase 1
    LOADS(B0, B1, B2, B3, 1);

    // ---- phase 0: per-thread ek' (cols k0..k0+7) + wave-uniform eq ----
    const int k0 = lane * 8;
    const size_t sbase = (size_t)h * MROWS + b * NSEQ;
    float4 s0 = *reinterpret_cast<const float4*>(&sk_t[sbase + k0]);
    float4 s1 = *reinterpret_cast<const float4*>(&sk_t[sbase + k0 + 4]);
    float4 p0 = *reinterpret_cast<const float4*>(&pmask[b * NSEQ + k0]);
    float4 p1 = *reinterpret_cast<const float4*>(&pmask[b * NSEQ + k0 + 4]);
    float skv[8] = {s0.x, s0.y, s0.z, s0.w, s1.x, s1.y, s1.z, s1.w};
    float pkv[8] = {p0.x, p0.y, p0.z, p0.w, p1.x, p1.y, p1.z, p1.w};
    float ek[8];
    #pragma unroll
    for (int j = 0; j < 8; j++)
        ek[j] = (pkv[j] > 0.f) ? __expf(2.f * skv[j]) : 0.f;

    float eq[4];
    #pragma unroll
    for (int g = 0; g < 4; g++) {
        int q = wave * 4 + g;
        float sqv = sq_t[sbase + q0 + q];
        float pqv = pmask[b * NSEQ + q0 + q];
        eq[g] = (pqv > 0.f) ? __expf(2.f * sqv) : 0.f;
    }

    // ---- phase 1: w[q][k] = exp(tanh(sq+sk)) via u=eq*ek + poly exp ----
    #pragma unroll
    for (int g = 0; g < 4; g++) {
        int q = wave * 4 + g;
        float eqv = eq[g];
        bf16x8 wv;
        #pragma unroll
        for (int j = 0; j < 8; j++) {
            float u  = eqv * ek[j];
            float tt = 1.f - 2.f * __builtin_amdgcn_rcpf(u + 1.f);  // tanh
            float pe = poly_exp6(tt);
            wv[j] = (__bf16)(u > 0.f ? pe : 1.0f);   // masked: exp(-1e-8) ~= 1
        }
        *reinterpret_cast<bf16x8*>(&w[q][k0]) = wv;
    }
    BAR_LGKM();                        // w visible; V loads stay in flight

    WRITEV(A0, A1, A2, A3);            // tile 0 (compiler waits its vmcnt)
    LOADS(A0, A1, A2, A3, 2);          // set A now carries tile 2
    BAR_LGKM();

    // ---- phase 2: PV via MFMA + ones-column row-sums ----
    const int wd0 = wave * 32;
    const int lr  = lane & 15;
    const int lg  = lane >> 4;

    bf16x8 vones;
    #pragma unroll
    for (int e = 0; e < 8; e++) vones[e] = (__bf16)1.0f;

    f32x4 acc[2] = {};
    f32x4 accs = {};

    #pragma unroll
    for (int t = 0; t < 8; t++) {
        #pragma unroll
        for (int ks = 0; ks < 2; ks++) {
            bf16x8 af = *reinterpret_cast<const bf16x8*>(&w[lr][t * 64 + ks * 32 + lg * 8]);
            #pragma unroll
            for (int n = 0; n < 2; n++) {
                int d    = wd0 + n * 16 + lr;
                int kbk  = ks * 4 + lg;
                int swzd = (d & 7) ^ ((d >> 3) & 7);
                bf16x8 bv = *reinterpret_cast<const bf16x8*>(vtb + d * 128 + ((kbk ^ swzd) << 4));
                acc[n] = __builtin_amdgcn_mfma_f32_16x16x32_bf16(af, bv, acc[n], 0, 0, 0);
            }
            accs = __builtin_amdgcn_mfma_f32_16x16x32_bf16(af, vones, accs, 0, 0, 0);
        }
        BAR_PLAIN();                   // all waves done reading tile t
        if (t < 7) {
            if ((t & 1) == 0) WRITEV(B0, B1, B2, B3);
            else              WRITEV(A0, A1, A2, A3);
        }
        if (t < 5) {
            if ((t & 1) == 0) LOADS(B0, B1, B2, B3, t + 3);
            else              LOADS(A0, A1, A2, A3, t + 3);
        }
        BAR_LGKM();
    }

    // ---- epilogue: rden lane-local (from ones-MFMA), tanh, +residual ----
    #pragma unroll
    for (int r = 0; r < 4; r++) {
        int ql = lg * 4 + r;
        float rden = __builtin_amdgcn_rcpf(accs[r]);
        #pragma unroll
        for (int n = 0; n < 2; n++) {
            int d  = wd0 + n * 16 + lr;
            float hv = acc[n][r] * rden;
            float e2 = __expf(2.f * hv);
            float tv = 1.f - 2.f * __builtin_amdgcn_rcpf(e2 + 1.f);   // tanh(hv)
            size_t o = ((size_t)(b * NSEQ + q0 + ql)) * DMODEL + (size_t)h * DHEAD + d;
            float ov = residual[o] + tv;
            out[o] = ov;
            if (out_bf) out_bf[o] = (__bf16)ov;
        }
    }
    #undef LOADS
    #undef WRITEV
}

extern "C" void kernel_launch(void* const* d_in, const int* in_sizes, int n_in,
                              void* d_out, int out_size, void* d_ws, size_t ws_size,
                              hipStream_t stream) {
    const float* pmask   = (const float*)d_in[0];
    const float* feature = (const float*)d_in[1];
    const float* W       = (const float*)d_in[2];
    const float* Wa      = (const float*)d_in[3];
    float* out = (float*)d_out;
    char* ws = (char*)d_ws;

    __bf16* Abf  = (__bf16*)ws;
    __bf16* Wbf  = (__bf16*)(ws + 12582912);
    __bf16* QKbf = (__bf16*)(ws + 12582912 + 1179648);
    float*  sq   = (float*)(ws + 12582912 + 1179648 + 12582912);
    float*  sk   = sq + MROWS * NHEAD;

    const int featN4 = (MROWS * DMODEL) / 4;
    const int wN4    = (DMODEL * DMODEL) / 4;

    hipLaunchKernelGGL(cvt_bf16_kernel, dim3((wN4 + 255) / 256), dim3(256), 0, stream,
                       W, Wbf, wN4);

    // ---- layer 1 ----
    hipLaunchKernelGGL(cvt_bf16_kernel, dim3((featN4 + 255) / 256), dim3(256), 0, stream,
                       feature, Abf, featN4);
    hipLaunchKernelGGL(gemm_bt, dim3(768), dim3(256), 0, stream,
                       Abf, Wbf, QKbf, Wa, sq, sk);
    hipLaunchKernelGGL(attn_pv, dim3(3072), dim3(256), 0, stream,
                       QKbf, sq, sk, pmask, feature, out, Abf);

    // ---- layer 2 ----
    hipLaunchKernelGGL(gemm_bt, dim3(768), dim3(256), 0, stream,
                       Abf, Wbf, QKbf, Wa, sq, sk);
    hipLaunchKernelGGL(attn_pv, dim3(3072), dim3(256), 0, stream,
                       QKbf, sq, sk, pmask, out, out, (__bf16*)nullptr);
}

// Round 7
// 128.059 us; speedup vs baseline: 1.2017x; 1.0926x over previous
//
#include <hip/hip_runtime.h>
#include <hip/hip_bf16.h>
#include <stdint.h>

// Problem constants (B=16, N=512, D=768, H=6, Dh=128, layers=2)
#define BATCH 16
#define NSEQ  512
#define DMODEL 768
#define NHEAD 6
#define DHEAD 128
#define MROWS (BATCH * NSEQ)   // 8192
#define QBLK  16
#define KTILE 64

typedef __attribute__((ext_vector_type(8))) __bf16 bf16x8;
typedef __attribute__((ext_vector_type(4))) __bf16 bf16x4;
typedef __attribute__((ext_vector_type(4))) float  f32x4;
typedef __attribute__((ext_vector_type(8))) unsigned short u16x8;

#define GLD16(gp, lp) __builtin_amdgcn_global_load_lds( \
    (const __attribute__((address_space(1))) unsigned int*)(gp), \
    (__attribute__((address_space(3))) unsigned int*)(lp), 16, 0, 0)

// raw barrier (does NOT drain vmcnt -> global loads stay in flight)
#define BAR_PLAIN() do { asm volatile("" ::: "memory"); \
    __builtin_amdgcn_s_barrier(); asm volatile("" ::: "memory"); } while (0)
// barrier with LDS-op flush (producer side of ds_write -> cross-wave read)
#define BAR_LGKM() do { asm volatile("s_waitcnt lgkmcnt(0)" ::: "memory"); \
    __builtin_amdgcn_s_barrier(); asm volatile("" ::: "memory"); } while (0)

// degree-6 Taylor exp(t) for t in [-1,1]; rel err <5e-4 (below bf16 rounding)
__device__ inline float poly_exp6(float t) {
    float p = 1.38888889e-3f;            // 1/720
    p = fmaf(p, t, 8.33333333e-3f);      // 1/120
    p = fmaf(p, t, 4.16666667e-2f);      // 1/24
    p = fmaf(p, t, 1.66666667e-1f);      // 1/6
    p = fmaf(p, t, 0.5f);
    p = fmaf(p, t, 1.0f);
    p = fmaf(p, t, 1.0f);
    return p;
}

// ---------------- fp32 -> bf16 conversion (vectorized x4) ----------------
__global__ void cvt_bf16_kernel(const float* __restrict__ src,
                                __bf16* __restrict__ dst, int n4) {
    int i = blockIdx.x * blockDim.x + threadIdx.x;
    if (i < n4) {
        float4 v = reinterpret_cast<const float4*>(src)[i];
        bf16x4 o;
        o.x = (__bf16)v.x; o.y = (__bf16)v.y; o.z = (__bf16)v.z; o.w = (__bf16)v.w;
        reinterpret_cast<bf16x4*>(dst)[i] = o;
    }
}

// ---------------- bf16 MFMA GEMM (64x128 tile) + fused sq/sk epilogue -----
__global__ __launch_bounds__(256) void gemm_bt(const __bf16* __restrict__ A,
                                               const __bf16* __restrict__ Bm,
                                               __bf16* __restrict__ C,
                                               const float* __restrict__ Wa,
                                               float* __restrict__ sq_t,
                                               float* __restrict__ sk_t) {
    __shared__ __align__(16) __bf16 As[2][64 * 32];
    __shared__ __align__(16) __bf16 Bs[2][128 * 32];
    const int tid  = threadIdx.x;
    const int lane = tid & 63;
    const int wave = tid >> 6;
    const int wm = wave >> 1, wn = wave & 1;   // wave: 32m x 64n

    const int wg  = blockIdx.x;
    const int nid = (wg & 7) * 96 + (wg >> 3);  // 768 = 8*96
    const int bx  = nid % 6;
    const int by  = nid / 6;
    const int m0 = by * 64;
    const int n0 = bx * 128;

    f32x4 acc[2][4] = {};

    const int e0   = tid * 8;
    const int row0 = tid >> 2;
    const int k0i  = (tid & 3) * 8;

    const int lr = lane & 15;
    const int lg = lane >> 4;
    const int kb = lg * 8;

    #define STAGE(kt, bufi) do { \
        GLD16(A  + (size_t)(m0 + row0)      * DMODEL + (kt) + k0i, &As[bufi][e0]); \
        GLD16(Bm + (size_t)(n0 + row0)      * DMODEL + (kt) + k0i, &Bs[bufi][e0]); \
        GLD16(Bm + (size_t)(n0 + row0 + 64) * DMODEL + (kt) + k0i, &Bs[bufi][e0 + 2048]); \
    } while (0)

    STAGE(0, 0);

    for (int t = 0; t < 24; t++) {
        const int buf = t & 1;
        if (t < 23) {
            STAGE((t + 1) * 32, buf ^ 1);
            asm volatile("s_waitcnt vmcnt(3)" ::: "memory");
        } else {
            asm volatile("s_waitcnt vmcnt(0)" ::: "memory");
        }
        __builtin_amdgcn_s_barrier();
        asm volatile("" ::: "memory");

        bf16x8 af[2], bfv[4];
        #pragma unroll
        for (int i = 0; i < 2; i++)
            af[i] = *reinterpret_cast<const bf16x8*>(&As[buf][(wm * 32 + i * 16 + lr) * 32 + kb]);
        #pragma unroll
        for (int j = 0; j < 4; j++)
            bfv[j] = *reinterpret_cast<const bf16x8*>(&Bs[buf][(wn * 64 + j * 16 + lr) * 32 + kb]);
        #pragma unroll
        for (int i = 0; i < 2; i++)
            #pragma unroll
            for (int j = 0; j < 4; j++)
                acc[i][j] = __builtin_amdgcn_mfma_f32_16x16x32_bf16(af[i], bfv[j], acc[i][j], 0, 0, 0);

        BAR_PLAIN();
    }
    #undef STAGE

    const int rg = lg * 4;
    #pragma unroll
    for (int i = 0; i < 2; i++) {
        #pragma unroll
        for (int j = 0; j < 4; j++) {
            #pragma unroll
            for (int r = 0; r < 4; r++) {
                int row = m0 + wm * 32 + i * 16 + rg + r;
                int col = n0 + wn * 64 + j * 16 + lr;
                C[(size_t)row * DMODEL + col] = (__bf16)acc[i][j][r];
            }
        }
    }

    // ---- fused sq/sk ----
    const int h = bx;
    float wqv[4], wkv[4];
    #pragma unroll
    for (int j = 0; j < 4; j++) {
        int d = wn * 64 + j * 16 + lr;
        wqv[j] = Wa[h * 256 + d];
        wkv[j] = Wa[h * 256 + 128 + d];
    }
    float* red = reinterpret_cast<float*>(&As[0][0]);
    #pragma unroll
    for (int i = 0; i < 2; i++) {
        #pragma unroll
        for (int r = 0; r < 4; r++) {
            float aq = 0.f, ak = 0.f;
            #pragma unroll
            for (int j = 0; j < 4; j++) {
                aq += acc[i][j][r] * wqv[j];
                ak += acc[i][j][r] * wkv[j];
            }
            #pragma unroll
            for (int off = 1; off < 16; off <<= 1) {
                aq += __shfl_xor(aq, off);
                ak += __shfl_xor(ak, off);
            }
            if (lr == 0) {
                int row = wm * 32 + i * 16 + rg + r;
                red[(0 * 64 + row) * 2 + wn] = aq;
                red[(1 * 64 + row) * 2 + wn] = ak;
            }
        }
    }
    __syncthreads();
    if (tid < 64) {
        sq_t[(size_t)h * MROWS + m0 + tid] = red[tid * 2] + red[tid * 2 + 1];
    } else if (tid < 128) {
        int row = tid - 64;
        sk_t[(size_t)h * MROWS + m0 + row] = red[(64 + row) * 2] + red[(64 + row) * 2 + 1];
    }
}

// ---------------- fused score/softmax/MFMA-PV/tanh/residual ----------------
// grid 3072 XCD-chunked; block 256 (4 waves). LDS exactly 32,768 B.
// w stored chunk-XOR-swizzled: storage col = k ^ ((q&7)<<3)  (conflict-free
// for both the row-contiguous writes and the 16-row A-frag reads).
__global__ __launch_bounds__(256) void attn_pv(const __bf16* __restrict__ QK,
                                               const float* __restrict__ sq_t,
                                               const float* __restrict__ sk_t,
                                               const float* __restrict__ pmask,
                                               const float* __restrict__ residual,
                                               float* __restrict__ out,
                                               __bf16* __restrict__ out_bf) {
    const int wg  = blockIdx.x;
    const int nid = (wg & 7) * 384 + (wg >> 3);   // bijective: 3072 = 8*384
    const int qt = nid & 31;          // 32 q-tiles of 16
    const int hb = nid >> 5;          // 0..95
    const int h  = hb % NHEAD;
    const int b  = hb / NHEAD;
    const int q0 = qt * QBLK;

    __shared__ __align__(16) __bf16 w[QBLK][512];        // 16,384 B (swizzled cols)
    __shared__ __align__(16) __bf16 Vt[DHEAD * KTILE];   // 16,384 B
    const int tid  = threadIdx.x;
    const int lane = tid & 63;
    const int wave = tid >> 6;

    const int wd0 = wave * 32;
    const int lr  = lane & 15;
    const int lg  = lane >> 4;

    // ---- phase 2 staging geometry; issue V tiles 0,1 EARLY ----
    const int sd0 = (tid & 15) * 8;
    const int sk0 = (tid >> 4) * 4;
    const __bf16* Vbase = QK + (size_t)b * NSEQ * DMODEL + (size_t)h * DHEAD + sd0;
    char* vtb = reinterpret_cast<char*>(&Vt[0]);

    u16x8 A0, A1, A2, A3, B0, B1, B2, B3;
    #define LOADS(S0, S1, S2, S3, t) do { \
        const __bf16* p = Vbase + (size_t)((t) * KTILE + sk0) * DMODEL; \
        S0 = *reinterpret_cast<const u16x8*>(p); \
        S1 = *reinterpret_cast<const u16x8*>(p + DMODEL); \
        S2 = *reinterpret_cast<const u16x8*>(p + 2 * DMODEL); \
        S3 = *reinterpret_cast<const u16x8*>(p + 3 * DMODEL); \
    } while (0)
    #define WRITEV(S0, S1, S2, S3) do { \
        _Pragma("unroll") \
        for (int j = 0; j < 8; j++) { \
            int d = sd0 + j; \
            int swz = j ^ (tid & 7); \
            unsigned long long pk = (unsigned long long)(unsigned short)S0[j] \
                                  | ((unsigned long long)(unsigned short)S1[j] << 16) \
                                  | ((unsigned long long)(unsigned short)S2[j] << 32) \
                                  | ((unsigned long long)(unsigned short)S3[j] << 48); \
            *reinterpret_cast<unsigned long long*>(vtb + d * 128 + ((sk0 ^ (swz << 3)) * 2)) = pk; \
        } \
    } while (0)

    LOADS(A0, A1, A2, A3, 0);          // latency hidden under phase 0/1
    LOADS(B0, B1, B2, B3, 1);

    // ---- early residual prefetch (epilogue operand; hides HBM latency) ----
    float res[4][2];
    #pragma unroll
    for (int r = 0; r < 4; r++) {
        int ql = lg * 4 + r;
        #pragma unroll
        for (int n = 0; n < 2; n++) {
            int d = wd0 + n * 16 + lr;
            res[r][n] = residual[((size_t)(b * NSEQ + q0 + ql)) * DMODEL + (size_t)h * DHEAD + d];
        }
    }

    // ---- phase 0: per-thread ek' (cols k0..k0+7) + wave-uniform eq ----
    const int k0 = lane * 8;
    const size_t sbase = (size_t)h * MROWS + b * NSEQ;
    float4 s0 = *reinterpret_cast<const float4*>(&sk_t[sbase + k0]);
    float4 s1 = *reinterpret_cast<const float4*>(&sk_t[sbase + k0 + 4]);
    float4 p0 = *reinterpret_cast<const float4*>(&pmask[b * NSEQ + k0]);
    float4 p1 = *reinterpret_cast<const float4*>(&pmask[b * NSEQ + k0 + 4]);
    float skv[8] = {s0.x, s0.y, s0.z, s0.w, s1.x, s1.y, s1.z, s1.w};
    float pkv[8] = {p0.x, p0.y, p0.z, p0.w, p1.x, p1.y, p1.z, p1.w};
    float ek[8];
    #pragma unroll
    for (int j = 0; j < 8; j++)
        ek[j] = (pkv[j] > 0.f) ? __expf(2.f * skv[j]) : 0.f;

    float eq[4];
    #pragma unroll
    for (int g = 0; g < 4; g++) {
        int q = wave * 4 + g;
        float sqv = sq_t[sbase + q0 + q];
        float pqv = pmask[b * NSEQ + q0 + q];
        eq[g] = (pqv > 0.f) ? __expf(2.f * sqv) : 0.f;
    }

    // ---- phase 1: w[q][k] = exp(tanh(sq+sk)) via u=eq*ek + poly exp ----
    #pragma unroll
    for (int g = 0; g < 4; g++) {
        int q = wave * 4 + g;
        float eqv = eq[g];
        bf16x8 wv;
        #pragma unroll
        for (int j = 0; j < 8; j++) {
            float u  = eqv * ek[j];
            float tt = 1.f - 2.f * __builtin_amdgcn_rcpf(u + 1.f);  // tanh
            float pe = poly_exp6(tt);
            wv[j] = (__bf16)(u > 0.f ? pe : 1.0f);   // masked: exp(-1e-8) ~= 1
        }
        *reinterpret_cast<bf16x8*>(&w[q][k0 ^ ((q & 7) << 3)]) = wv;   // swizzled store
    }
    BAR_LGKM();                        // w visible; V loads stay in flight

    WRITEV(A0, A1, A2, A3);            // tile 0 (compiler waits its vmcnt)
    LOADS(A0, A1, A2, A3, 2);          // set A now carries tile 2
    BAR_LGKM();

    // ---- phase 2: PV via MFMA + ones-column row-sums ----
    bf16x8 vones;
    #pragma unroll
    for (int e = 0; e < 8; e++) vones[e] = (__bf16)1.0f;

    f32x4 acc[2] = {};
    f32x4 accs = {};

    const int wswz = (lr & 7) << 3;    // per-lane w col swizzle

    #pragma unroll
    for (int t = 0; t < 8; t++) {
        __builtin_amdgcn_s_setprio(1);
        #pragma unroll
        for (int ks = 0; ks < 2; ks++) {
            bf16x8 af = *reinterpret_cast<const bf16x8*>(&w[lr][(t * 64 + ks * 32 + lg * 8) ^ wswz]);
            #pragma unroll
            for (int n = 0; n < 2; n++) {
                int d    = wd0 + n * 16 + lr;
                int kbk  = ks * 4 + lg;
                int swzd = (d & 7) ^ ((d >> 3) & 7);
                bf16x8 bv = *reinterpret_cast<const bf16x8*>(vtb + d * 128 + ((kbk ^ swzd) << 4));
                acc[n] = __builtin_amdgcn_mfma_f32_16x16x32_bf16(af, bv, acc[n], 0, 0, 0);
            }
            accs = __builtin_amdgcn_mfma_f32_16x16x32_bf16(af, vones, accs, 0, 0, 0);
        }
        __builtin_amdgcn_s_setprio(0);
        BAR_PLAIN();                   // all waves done reading tile t
        if (t < 7) {
            if ((t & 1) == 0) WRITEV(B0, B1, B2, B3);
            else              WRITEV(A0, A1, A2, A3);
        }
        if (t < 5) {
            if ((t & 1) == 0) LOADS(B0, B1, B2, B3, t + 3);
            else              LOADS(A0, A1, A2, A3, t + 3);
        }
        BAR_LGKM();
    }

    // ---- epilogue: rden lane-local (from ones-MFMA), tanh, +residual ----
    #pragma unroll
    for (int r = 0; r < 4; r++) {
        int ql = lg * 4 + r;
        float rden = __builtin_amdgcn_rcpf(accs[r]);
        #pragma unroll
        for (int n = 0; n < 2; n++) {
            int d  = wd0 + n * 16 + lr;
            float hv = acc[n][r] * rden;
            float e2 = __expf(2.f * hv);
            float tv = 1.f - 2.f * __builtin_amdgcn_rcpf(e2 + 1.f);   // tanh(hv)
            size_t o = ((size_t)(b * NSEQ + q0 + ql)) * DMODEL + (size_t)h * DHEAD + d;
            float ov = res[r][n] + tv;
            out[o] = ov;
            if (out_bf) out_bf[o] = (__bf16)ov;
        }
    }
    #undef LOADS
    #undef WRITEV
}

extern "C" void kernel_launch(void* const* d_in, const int* in_sizes, int n_in,
                              void* d_out, int out_size, void* d_ws, size_t ws_size,
                              hipStream_t stream) {
    const float* pmask   = (const float*)d_in[0];
    const float* feature = (const float*)d_in[1];
    const float* W       = (const float*)d_in[2];
    const float* Wa      = (const float*)d_in[3];
    float* out = (float*)d_out;
    char* ws = (char*)d_ws;

    __bf16* Abf  = (__bf16*)ws;
    __bf16* Wbf  = (__bf16*)(ws + 12582912);
    __bf16* QKbf = (__bf16*)(ws + 12582912 + 1179648);
    float*  sq   = (float*)(ws + 12582912 + 1179648 + 12582912);
    float*  sk   = sq + MROWS * NHEAD;

    const int featN4 = (MROWS * DMODEL) / 4;
    const int wN4    = (DMODEL * DMODEL) / 4;

    hipLaunchKernelGGL(cvt_bf16_kernel, dim3((wN4 + 255) / 256), dim3(256), 0, stream,
                       W, Wbf, wN4);

    // ---- layer 1 ----
    hipLaunchKernelGGL(cvt_bf16_kernel, dim3((featN4 + 255) / 256), dim3(256), 0, stream,
                       feature, Abf, featN4);
    hipLaunchKernelGGL(gemm_bt, dim3(768), dim3(256), 0, stream,
                       Abf, Wbf, QKbf, Wa, sq, sk);
    hipLaunchKernelGGL(attn_pv, dim3(3072), dim3(256), 0, stream,
                       QKbf, sq, sk, pmask, feature, out, Abf);

    // ---- layer 2 ----
    hipLaunchKernelGGL(gemm_bt, dim3(768), dim3(256), 0, stream,
                       Abf, Wbf, QKbf, Wa, sq, sk);
    hipLaunchKernelGGL(attn_pv, dim3(3072), dim3(256), 0, stream,
                       QKbf, sq, sk, pmask, out, out, (__bf16*)nullptr);
}

// Round 8
// 119.632 us; speedup vs baseline: 1.2863x; 1.0704x over previous
//
#include <hip/hip_runtime.h>
#include <hip/hip_bf16.h>
#include <stdint.h>

// Problem constants (B=16, N=512, D=768, H=6, Dh=128, layers=2)
#define BATCH 16
#define NSEQ  512
#define DMODEL 768
#define NHEAD 6
#define DHEAD 128
#define MROWS (BATCH * NSEQ)   // 8192
#define QBLK  16
#define KTILE 64

typedef __attribute__((ext_vector_type(8))) __bf16 bf16x8;
typedef __attribute__((ext_vector_type(4))) __bf16 bf16x4;
typedef __attribute__((ext_vector_type(4))) float  f32x4;
typedef __attribute__((ext_vector_type(4))) unsigned int u32x4;

#define GLD16(gp, lp) __builtin_amdgcn_global_load_lds( \
    (const __attribute__((address_space(1))) unsigned int*)(gp), \
    (__attribute__((address_space(3))) unsigned int*)(lp), 16, 0, 0)

// raw barrier (does NOT drain vmcnt -> global loads stay in flight)
#define BAR_PLAIN() do { asm volatile("" ::: "memory"); \
    __builtin_amdgcn_s_barrier(); asm volatile("" ::: "memory"); } while (0)
// barrier with LDS-op flush (producer side of ds_write -> cross-wave read)
#define BAR_LGKM() do { asm volatile("s_waitcnt lgkmcnt(0)" ::: "memory"); \
    __builtin_amdgcn_s_barrier(); asm volatile("" ::: "memory"); } while (0)

// ---------------- fp32 -> bf16 conversion (vectorized x4) ----------------
__global__ void cvt_bf16_kernel(const float* __restrict__ src,
                                __bf16* __restrict__ dst, int n4) {
    int i = blockIdx.x * blockDim.x + threadIdx.x;
    if (i < n4) {
        float4 v = reinterpret_cast<const float4*>(src)[i];
        bf16x4 o;
        o.x = (__bf16)v.x; o.y = (__bf16)v.y; o.z = (__bf16)v.z; o.w = (__bf16)v.w;
        reinterpret_cast<bf16x4*>(dst)[i] = o;
    }
}

// ---------------- bf16 MFMA GEMM (64x128 tile) + fused eq/ek epilogue -----
// Stores eq = pmask * exp(2*sq), ek = pmask * exp(2*sk) directly (attn's
// score phase then needs no transcendentals for the broadcast terms).
__global__ __launch_bounds__(256) void gemm_bt(const __bf16* __restrict__ A,
                                               const __bf16* __restrict__ Bm,
                                               __bf16* __restrict__ C,
                                               const float* __restrict__ Wa,
                                               const float* __restrict__ pmask,
                                               float* __restrict__ eq_t,
                                               float* __restrict__ ek_t) {
    __shared__ __align__(16) __bf16 As[2][64 * 32];
    __shared__ __align__(16) __bf16 Bs[2][128 * 32];
    const int tid  = threadIdx.x;
    const int lane = tid & 63;
    const int wave = tid >> 6;
    const int wm = wave >> 1, wn = wave & 1;   // wave: 32m x 64n

    const int wg  = blockIdx.x;
    const int nid = (wg & 7) * 96 + (wg >> 3);  // 768 = 8*96
    const int bx  = nid % 6;
    const int by  = nid / 6;
    const int m0 = by * 64;
    const int n0 = bx * 128;

    f32x4 acc[2][4] = {};

    const int e0   = tid * 8;
    const int row0 = tid >> 2;
    const int k0i  = (tid & 3) * 8;

    const int lr = lane & 15;
    const int lg = lane >> 4;
    const int kb = lg * 8;

    #define STAGE(kt, bufi) do { \
        GLD16(A  + (size_t)(m0 + row0)      * DMODEL + (kt) + k0i, &As[bufi][e0]); \
        GLD16(Bm + (size_t)(n0 + row0)      * DMODEL + (kt) + k0i, &Bs[bufi][e0]); \
        GLD16(Bm + (size_t)(n0 + row0 + 64) * DMODEL + (kt) + k0i, &Bs[bufi][e0 + 2048]); \
    } while (0)

    STAGE(0, 0);

    for (int t = 0; t < 24; t++) {
        const int buf = t & 1;
        if (t < 23) {
            STAGE((t + 1) * 32, buf ^ 1);
            asm volatile("s_waitcnt vmcnt(3)" ::: "memory");
        } else {
            asm volatile("s_waitcnt vmcnt(0)" ::: "memory");
        }
        __builtin_amdgcn_s_barrier();
        asm volatile("" ::: "memory");

        bf16x8 af[2], bfv[4];
        #pragma unroll
        for (int i = 0; i < 2; i++)
            af[i] = *reinterpret_cast<const bf16x8*>(&As[buf][(wm * 32 + i * 16 + lr) * 32 + kb]);
        #pragma unroll
        for (int j = 0; j < 4; j++)
            bfv[j] = *reinterpret_cast<const bf16x8*>(&Bs[buf][(wn * 64 + j * 16 + lr) * 32 + kb]);
        #pragma unroll
        for (int i = 0; i < 2; i++)
            #pragma unroll
            for (int j = 0; j < 4; j++)
                acc[i][j] = __builtin_amdgcn_mfma_f32_16x16x32_bf16(af[i], bfv[j], acc[i][j], 0, 0, 0);

        BAR_PLAIN();
    }
    #undef STAGE

    const int rg = lg * 4;
    #pragma unroll
    for (int i = 0; i < 2; i++) {
        #pragma unroll
        for (int j = 0; j < 4; j++) {
            #pragma unroll
            for (int r = 0; r < 4; r++) {
                int row = m0 + wm * 32 + i * 16 + rg + r;
                int col = n0 + wn * 64 + j * 16 + lr;
                C[(size_t)row * DMODEL + col] = (__bf16)acc[i][j][r];
            }
        }
    }

    // ---- fused sq/sk reduction ----
    const int h = bx;
    float wqv[4], wkv[4];
    #pragma unroll
    for (int j = 0; j < 4; j++) {
        int d = wn * 64 + j * 16 + lr;
        wqv[j] = Wa[h * 256 + d];
        wkv[j] = Wa[h * 256 + 128 + d];
    }
    float* red = reinterpret_cast<float*>(&As[0][0]);
    #pragma unroll
    for (int i = 0; i < 2; i++) {
        #pragma unroll
        for (int r = 0; r < 4; r++) {
            float aq = 0.f, ak = 0.f;
            #pragma unroll
            for (int j = 0; j < 4; j++) {
                aq += acc[i][j][r] * wqv[j];
                ak += acc[i][j][r] * wkv[j];
            }
            #pragma unroll
            for (int off = 1; off < 16; off <<= 1) {
                aq += __shfl_xor(aq, off);
                ak += __shfl_xor(ak, off);
            }
            if (lr == 0) {
                int row = wm * 32 + i * 16 + rg + r;
                red[(0 * 64 + row) * 2 + wn] = aq;
                red[(1 * 64 + row) * 2 + wn] = ak;
            }
        }
    }
    __syncthreads();
    if (tid < 64) {
        int row = m0 + tid;
        float s = red[tid * 2] + red[tid * 2 + 1];
        eq_t[(size_t)h * MROWS + row] = (pmask[row] > 0.f) ? __expf(2.f * s) : 0.f;
    } else if (tid < 128) {
        int rl  = tid - 64;
        int row = m0 + rl;
        float s = red[(64 + rl) * 2] + red[(64 + rl) * 2 + 1];
        ek_t[(size_t)h * MROWS + row] = (pmask[row] > 0.f) ? __expf(2.f * s) : 0.f;
    }
}

// ---------------- fused score/softmax/MFMA-PV/tanh/residual ----------------
// grid 3072 XCD-chunked; block 256 (4 waves). LDS exactly 32,768 B.
__global__ __launch_bounds__(256) void attn_pv(const __bf16* __restrict__ QK,
                                               const float* __restrict__ eq_t,
                                               const float* __restrict__ ek_t,
                                               const float* __restrict__ residual,
                                               float* __restrict__ out,
                                               __bf16* __restrict__ out_bf) {
    const int wg  = blockIdx.x;
    const int nid = (wg & 7) * 384 + (wg >> 3);   // bijective: 3072 = 8*384
    const int qt = nid & 31;          // 32 q-tiles of 16
    const int hb = nid >> 5;          // 0..95
    const int h  = hb % NHEAD;
    const int b  = hb / NHEAD;
    const int q0 = qt * QBLK;

    __shared__ __align__(16) __bf16 w[QBLK][512];        // 16,384 B (swizzled cols)
    __shared__ __align__(16) __bf16 Vt[DHEAD * KTILE];   // 16,384 B
    const int tid  = threadIdx.x;
    const int lane = tid & 63;
    const int wave = tid >> 6;

    const int wd0 = wave * 32;
    const int lr  = lane & 15;
    const int lg  = lane >> 4;

    // ---- phase 2 staging geometry; issue V tiles 0,1 EARLY ----
    const int sd0 = (tid & 15) * 8;
    const int sk0 = (tid >> 4) * 4;
    const __bf16* Vbase = QK + (size_t)b * NSEQ * DMODEL + (size_t)h * DHEAD + sd0;
    char* vtb = reinterpret_cast<char*>(&Vt[0]);

    u32x4 A0, A1, A2, A3, B0, B1, B2, B3;
    #define LOADS(S0, S1, S2, S3, t) do { \
        const __bf16* p = Vbase + (size_t)((t) * KTILE + sk0) * DMODEL; \
        S0 = *reinterpret_cast<const u32x4*>(p); \
        S1 = *reinterpret_cast<const u32x4*>(p + DMODEL); \
        S2 = *reinterpret_cast<const u32x4*>(p + 2 * DMODEL); \
        S3 = *reinterpret_cast<const u32x4*>(p + 3 * DMODEL); \
    } while (0)
    // pack 4 k-values per d via v_perm (2 perms per b64 instead of shift/or chain)
    #define WRITEV(S0, S1, S2, S3) do { \
        _Pragma("unroll") \
        for (int j = 0; j < 8; j++) { \
            int d = sd0 + j; \
            int swz = j ^ (tid & 7); \
            unsigned sel = (j & 1) ? 0x07060302u : 0x05040100u; \
            unsigned lo = __builtin_amdgcn_perm(S1[j >> 1], S0[j >> 1], sel); \
            unsigned hi = __builtin_amdgcn_perm(S3[j >> 1], S2[j >> 1], sel); \
            unsigned long long pk = (unsigned long long)lo | ((unsigned long long)hi << 32); \
            *reinterpret_cast<unsigned long long*>(vtb + d * 128 + ((sk0 ^ (swz << 3)) * 2)) = pk; \
        } \
    } while (0)

    LOADS(A0, A1, A2, A3, 0);          // latency hidden under phase 0/1
    LOADS(B0, B1, B2, B3, 1);

    // ---- early residual prefetch (epilogue operand) ----
    float res[4][2];
    #pragma unroll
    for (int r = 0; r < 4; r++) {
        int ql = lg * 4 + r;
        #pragma unroll
        for (int n = 0; n < 2; n++) {
            int d = wd0 + n * 16 + lr;
            res[r][n] = residual[((size_t)(b * NSEQ + q0 + ql)) * DMODEL + (size_t)h * DHEAD + d];
        }
    }

    // ---- phase 0: pure loads (exp done in gemm epilogue; mask folded) ----
    const int k0 = lane * 8;
    const size_t sbase = (size_t)h * MROWS + b * NSEQ;
    float4 e0v = *reinterpret_cast<const float4*>(&ek_t[sbase + k0]);
    float4 e1v = *reinterpret_cast<const float4*>(&ek_t[sbase + k0 + 4]);
    float ek[8] = {e0v.x, e0v.y, e0v.z, e0v.w, e1v.x, e1v.y, e1v.z, e1v.w};
    float eq[4];
    #pragma unroll
    for (int g = 0; g < 4; g++)
        eq[g] = eq_t[sbase + q0 + wave * 4 + g];

    // ---- stage tile 0 into Vt (waits only A-regs; later loads in flight) ----
    WRITEV(A0, A1, A2, A3);
    LOADS(A0, A1, A2, A3, 2);          // set A now carries tile 2

    // ---- phase 1: w[q][k] = exp(tanh) = e^{1-2z}, z = rcp(u+1), u = eq*ek ----
    #pragma unroll
    for (int g = 0; g < 4; g++) {
        int q = wave * 4 + g;
        float eqv = eq[g];
        bf16x8 wv;
        #pragma unroll
        for (int j = 0; j < 8; j++) {
            float u = eqv * ek[j];
            float z = __builtin_amdgcn_rcpf(u + 1.f);
            float p = __expf(fmaf(z, -2.f, 1.f));
            wv[j] = (__bf16)(u > 0.f ? p : 1.0f);   // masked: exp(-1e-8) ~= 1
        }
        *reinterpret_cast<bf16x8*>(&w[q][k0 ^ ((q & 7) << 3)]) = wv;   // swizzled store
    }
    BAR_LGKM();                        // one barrier flushes w + Vt writes

    // ---- phase 2: PV via MFMA + ones-column row-sums ----
    bf16x8 vones;
    #pragma unroll
    for (int e = 0; e < 8; e++) vones[e] = (__bf16)1.0f;

    f32x4 acc[2] = {};
    f32x4 accs = {};

    const int wswz = (lr & 7) << 3;    // per-lane w col swizzle

    #pragma unroll
    for (int t = 0; t < 8; t++) {
        __builtin_amdgcn_s_setprio(1);
        #pragma unroll
        for (int ks = 0; ks < 2; ks++) {
            bf16x8 af = *reinterpret_cast<const bf16x8*>(&w[lr][(t * 64 + ks * 32 + lg * 8) ^ wswz]);
            #pragma unroll
            for (int n = 0; n < 2; n++) {
                int d    = wd0 + n * 16 + lr;
                int kbk  = ks * 4 + lg;
                int swzd = (d & 7) ^ ((d >> 3) & 7);
                bf16x8 bv = *reinterpret_cast<const bf16x8*>(vtb + d * 128 + ((kbk ^ swzd) << 4));
                acc[n] = __builtin_amdgcn_mfma_f32_16x16x32_bf16(af, bv, acc[n], 0, 0, 0);
            }
            accs = __builtin_amdgcn_mfma_f32_16x16x32_bf16(af, vones, accs, 0, 0, 0);
        }
        __builtin_amdgcn_s_setprio(0);
        BAR_PLAIN();                   // all waves done reading tile t
        if (t < 7) {
            if ((t & 1) == 0) WRITEV(B0, B1, B2, B3);
            else              WRITEV(A0, A1, A2, A3);
        }
        if (t < 5) {
            if ((t & 1) == 0) LOADS(B0, B1, B2, B3, t + 3);
            else              LOADS(A0, A1, A2, A3, t + 3);
        }
        BAR_LGKM();
    }

    // ---- epilogue: rden lane-local (from ones-MFMA), tanh, +residual ----
    #pragma unroll
    for (int r = 0; r < 4; r++) {
        int ql = lg * 4 + r;
        float rden = __builtin_amdgcn_rcpf(accs[r]);
        #pragma unroll
        for (int n = 0; n < 2; n++) {
            int d  = wd0 + n * 16 + lr;
            float hv = acc[n][r] * rden;
            float e2 = __expf(2.f * hv);
            float tv = 1.f - 2.f * __builtin_amdgcn_rcpf(e2 + 1.f);   // tanh(hv)
            size_t o = ((size_t)(b * NSEQ + q0 + ql)) * DMODEL + (size_t)h * DHEAD + d;
            float ov = res[r][n] + tv;
            out[o] = ov;
            if (out_bf) out_bf[o] = (__bf16)ov;
        }
    }
    #undef LOADS
    #undef WRITEV
}

extern "C" void kernel_launch(void* const* d_in, const int* in_sizes, int n_in,
                              void* d_out, int out_size, void* d_ws, size_t ws_size,
                              hipStream_t stream) {
    const float* pmask   = (const float*)d_in[0];
    const float* feature = (const float*)d_in[1];
    const float* W       = (const float*)d_in[2];
    const float* Wa      = (const float*)d_in[3];
    float* out = (float*)d_out;
    char* ws = (char*)d_ws;

    __bf16* Abf  = (__bf16*)ws;
    __bf16* Wbf  = (__bf16*)(ws + 12582912);
    __bf16* QKbf = (__bf16*)(ws + 12582912 + 1179648);
    float*  eq   = (float*)(ws + 12582912 + 1179648 + 12582912);
    float*  ek   = eq + MROWS * NHEAD;

    const int featN4 = (MROWS * DMODEL) / 4;
    const int wN4    = (DMODEL * DMODEL) / 4;

    hipLaunchKernelGGL(cvt_bf16_kernel, dim3((wN4 + 255) / 256), dim3(256), 0, stream,
                       W, Wbf, wN4);

    // ---- layer 1 ----
    hipLaunchKernelGGL(cvt_bf16_kernel, dim3((featN4 + 255) / 256), dim3(256), 0, stream,
                       feature, Abf, featN4);
    hipLaunchKernelGGL(gemm_bt, dim3(768), dim3(256), 0, stream,
                       Abf, Wbf, QKbf, Wa, pmask, eq, ek);
    hipLaunchKernelGGL(attn_pv, dim3(3072), dim3(256), 0, stream,
                       QKbf, eq, ek, feature, out, Abf);

    // ---- layer 2 ----
    hipLaunchKernelGGL(gemm_bt, dim3(768), dim3(256), 0, stream,
                       Abf, Wbf, QKbf, Wa, pmask, eq, ek);
    hipLaunchKernelGGL(attn_pv, dim3(3072), dim3(256), 0, stream,
                       QKbf, eq, ek, out, out, (__bf16*)nullptr);
}

// Round 9
// 110.394 us; speedup vs baseline: 1.3940x; 1.0837x over previous
//
#include <hip/hip_runtime.h>
#include <hip/hip_bf16.h>
#include <stdint.h>

// Problem constants (B=16, N=512, D=768, H=6, Dh=128, layers=2)
#define BATCH 16
#define NSEQ  512
#define DMODEL 768
#define NHEAD 6
#define DHEAD 128
#define MROWS (BATCH * NSEQ)   // 8192
#define QBLK  32
#define KTILE 64

typedef __attribute__((ext_vector_type(8))) __bf16 bf16x8;
typedef __attribute__((ext_vector_type(4))) __bf16 bf16x4;
typedef __attribute__((ext_vector_type(4))) float  f32x4;
typedef __attribute__((ext_vector_type(4))) unsigned int u32x4;

#define GLD16(gp, lp) __builtin_amdgcn_global_load_lds( \
    (const __attribute__((address_space(1))) unsigned int*)(gp), \
    (__attribute__((address_space(3))) unsigned int*)(lp), 16, 0, 0)

// raw barrier (does NOT drain vmcnt -> global loads stay in flight)
#define BAR_PLAIN() do { asm volatile("" ::: "memory"); \
    __builtin_amdgcn_s_barrier(); asm volatile("" ::: "memory"); } while (0)
// barrier with LDS-op flush (producer side of ds_write -> cross-wave read)
#define BAR_LGKM() do { asm volatile("s_waitcnt lgkmcnt(0)" ::: "memory"); \
    __builtin_amdgcn_s_barrier(); asm volatile("" ::: "memory"); } while (0)

// ---------------- fp32 -> bf16 conversion (vectorized x4) ----------------
__global__ void cvt_bf16_kernel(const float* __restrict__ src,
                                __bf16* __restrict__ dst, int n4) {
    int i = blockIdx.x * blockDim.x + threadIdx.x;
    if (i < n4) {
        float4 v = reinterpret_cast<const float4*>(src)[i];
        bf16x4 o;
        o.x = (__bf16)v.x; o.y = (__bf16)v.y; o.z = (__bf16)v.z; o.w = (__bf16)v.w;
        reinterpret_cast<bf16x4*>(dst)[i] = o;
    }
}

// ---------------- bf16 MFMA GEMM (64x128 tile) + fused eq/ek epilogue -----
__global__ __launch_bounds__(256) void gemm_bt(const __bf16* __restrict__ A,
                                               const __bf16* __restrict__ Bm,
                                               __bf16* __restrict__ C,
                                               const float* __restrict__ Wa,
                                               const float* __restrict__ pmask,
                                               float* __restrict__ eq_t,
                                               float* __restrict__ ek_t) {
    __shared__ __align__(16) __bf16 As[2][64 * 32];
    __shared__ __align__(16) __bf16 Bs[2][128 * 32];
    const int tid  = threadIdx.x;
    const int lane = tid & 63;
    const int wave = tid >> 6;
    const int wm = wave >> 1, wn = wave & 1;   // wave: 32m x 64n

    const int wg  = blockIdx.x;
    const int nid = (wg & 7) * 96 + (wg >> 3);  // 768 = 8*96
    const int bx  = nid % 6;
    const int by  = nid / 6;
    const int m0 = by * 64;
    const int n0 = bx * 128;

    f32x4 acc[2][4] = {};

    const int e0   = tid * 8;
    const int row0 = tid >> 2;
    const int k0i  = (tid & 3) * 8;

    const int lr = lane & 15;
    const int lg = lane >> 4;
    const int kb = lg * 8;

    #define STAGE(kt, bufi) do { \
        GLD16(A  + (size_t)(m0 + row0)      * DMODEL + (kt) + k0i, &As[bufi][e0]); \
        GLD16(Bm + (size_t)(n0 + row0)      * DMODEL + (kt) + k0i, &Bs[bufi][e0]); \
        GLD16(Bm + (size_t)(n0 + row0 + 64) * DMODEL + (kt) + k0i, &Bs[bufi][e0 + 2048]); \
    } while (0)

    STAGE(0, 0);

    for (int t = 0; t < 24; t++) {
        const int buf = t & 1;
        if (t < 23) {
            STAGE((t + 1) * 32, buf ^ 1);
            asm volatile("s_waitcnt vmcnt(3)" ::: "memory");
        } else {
            asm volatile("s_waitcnt vmcnt(0)" ::: "memory");
        }
        __builtin_amdgcn_s_barrier();
        asm volatile("" ::: "memory");

        bf16x8 af[2], bfv[4];
        #pragma unroll
        for (int i = 0; i < 2; i++)
            af[i] = *reinterpret_cast<const bf16x8*>(&As[buf][(wm * 32 + i * 16 + lr) * 32 + kb]);
        #pragma unroll
        for (int j = 0; j < 4; j++)
            bfv[j] = *reinterpret_cast<const bf16x8*>(&Bs[buf][(wn * 64 + j * 16 + lr) * 32 + kb]);
        #pragma unroll
        for (int i = 0; i < 2; i++)
            #pragma unroll
            for (int j = 0; j < 4; j++)
                acc[i][j] = __builtin_amdgcn_mfma_f32_16x16x32_bf16(af[i], bfv[j], acc[i][j], 0, 0, 0);

        BAR_PLAIN();
    }
    #undef STAGE

    const int rg = lg * 4;
    #pragma unroll
    for (int i = 0; i < 2; i++) {
        #pragma unroll
        for (int j = 0; j < 4; j++) {
            #pragma unroll
            for (int r = 0; r < 4; r++) {
                int row = m0 + wm * 32 + i * 16 + rg + r;
                int col = n0 + wn * 64 + j * 16 + lr;
                C[(size_t)row * DMODEL + col] = (__bf16)acc[i][j][r];
            }
        }
    }

    // ---- fused sq/sk reduction -> eq = pm*e^{2sq}, ek = pm*e^{2sk} ----
    const int h = bx;
    float wqv[4], wkv[4];
    #pragma unroll
    for (int j = 0; j < 4; j++) {
        int d = wn * 64 + j * 16 + lr;
        wqv[j] = Wa[h * 256 + d];
        wkv[j] = Wa[h * 256 + 128 + d];
    }
    float* red = reinterpret_cast<float*>(&As[0][0]);
    #pragma unroll
    for (int i = 0; i < 2; i++) {
        #pragma unroll
        for (int r = 0; r < 4; r++) {
            float aq = 0.f, ak = 0.f;
            #pragma unroll
            for (int j = 0; j < 4; j++) {
                aq += acc[i][j][r] * wqv[j];
                ak += acc[i][j][r] * wkv[j];
            }
            #pragma unroll
            for (int off = 1; off < 16; off <<= 1) {
                aq += __shfl_xor(aq, off);
                ak += __shfl_xor(ak, off);
            }
            if (lr == 0) {
                int row = wm * 32 + i * 16 + rg + r;
                red[(0 * 64 + row) * 2 + wn] = aq;
                red[(1 * 64 + row) * 2 + wn] = ak;
            }
        }
    }
    __syncthreads();
    if (tid < 64) {
        int row = m0 + tid;
        float s = red[tid * 2] + red[tid * 2 + 1];
        eq_t[(size_t)h * MROWS + row] = (pmask[row] > 0.f) ? __expf(2.f * s) : 0.f;
    } else if (tid < 128) {
        int rl  = tid - 64;
        int row = m0 + rl;
        float s = red[(64 + rl) * 2] + red[(64 + rl) * 2 + 1];
        ek_t[(size_t)h * MROWS + row] = (pmask[row] > 0.f) ? __expf(2.f * s) : 0.f;
    }
}

// ---------------- fused score/softmax/MFMA-PV/tanh/residual ----------------
// grid 1536 XCD-chunked; block 256 (4 waves). QBLK=32: each wave computes
// both 16-q halves against ONE bv read (halves per-Q V traffic).
// LDS = w[32][512] (32KB, XOR-swz) + Vt dbuf (2x16KB) = 64KB; 1 barrier/tile.
__global__ __launch_bounds__(256) void attn_pv(const __bf16* __restrict__ QK,
                                               const float* __restrict__ eq_t,
                                               const float* __restrict__ ek_t,
                                               const float* __restrict__ residual,
                                               float* __restrict__ out,
                                               __bf16* __restrict__ out_bf) {
    const int wg  = blockIdx.x;
    const int nid = (wg & 7) * 192 + (wg >> 3);   // bijective: 1536 = 8*192
    const int qt = nid & 15;          // 16 q-tiles of 32
    const int hb = nid >> 4;          // 0..95
    const int h  = hb % NHEAD;
    const int b  = hb / NHEAD;
    const int q0 = qt * QBLK;

    __shared__ __align__(16) __bf16 w[QBLK][512];            // 32,768 B (swizzled cols)
    __shared__ __align__(16) __bf16 Vt[2][DHEAD * KTILE];    // 2 x 16,384 B
    const int tid  = threadIdx.x;
    const int lane = tid & 63;
    const int wave = tid >> 6;

    const int wd0 = wave * 32;
    const int lr  = lane & 15;
    const int lg  = lane >> 4;

    // ---- staging geometry; issue V tiles 0,1 EARLY ----
    const int sd0 = (tid & 15) * 8;
    const int sk0 = (tid >> 4) * 4;
    const __bf16* Vbase = QK + (size_t)b * NSEQ * DMODEL + (size_t)h * DHEAD + sd0;

    u32x4 A0, A1, A2, A3, B0, B1, B2, B3;
    #define LOADS(S0, S1, S2, S3, t) do { \
        const __bf16* p = Vbase + (size_t)((t) * KTILE + sk0) * DMODEL; \
        S0 = *reinterpret_cast<const u32x4*>(p); \
        S1 = *reinterpret_cast<const u32x4*>(p + DMODEL); \
        S2 = *reinterpret_cast<const u32x4*>(p + 2 * DMODEL); \
        S3 = *reinterpret_cast<const u32x4*>(p + 3 * DMODEL); \
    } while (0)
    // pack 4 k per d via v_perm; Vt row=d (128B), col = k ^ (8*((d&7)^((d>>3)&7)))
    #define WRITEV(S0, S1, S2, S3, bufi) do { \
        char* vtw = reinterpret_cast<char*>(&Vt[bufi][0]); \
        _Pragma("unroll") \
        for (int j = 0; j < 8; j++) { \
            int d = sd0 + j; \
            int swz = j ^ (tid & 7); \
            unsigned sel = (j & 1) ? 0x07060302u : 0x05040100u; \
            unsigned lo = __builtin_amdgcn_perm(S1[j >> 1], S0[j >> 1], sel); \
            unsigned hi = __builtin_amdgcn_perm(S3[j >> 1], S2[j >> 1], sel); \
            unsigned long long pk = (unsigned long long)lo | ((unsigned long long)hi << 32); \
            *reinterpret_cast<unsigned long long*>(vtw + d * 128 + ((sk0 ^ (swz << 3)) * 2)) = pk; \
        } \
    } while (0)

    LOADS(A0, A1, A2, A3, 0);          // latency hidden under phase 0/1
    LOADS(B0, B1, B2, B3, 1);

    // ---- early residual prefetch (epilogue operand) ----
    float res[2][4][2];
    #pragma unroll
    for (int qh = 0; qh < 2; qh++) {
        #pragma unroll
        for (int r = 0; r < 4; r++) {
            int ql = qh * 16 + lg * 4 + r;
            #pragma unroll
            for (int n = 0; n < 2; n++) {
                int d = wd0 + n * 16 + lr;
                res[qh][r][n] = residual[((size_t)(b * NSEQ + q0 + ql)) * DMODEL + (size_t)h * DHEAD + d];
            }
        }
    }

    // ---- phase 0: pure loads (exp done in gemm epilogue; mask folded) ----
    const int k0 = lane * 8;
    const size_t sbase = (size_t)h * MROWS + b * NSEQ;
    float4 e0v = *reinterpret_cast<const float4*>(&ek_t[sbase + k0]);
    float4 e1v = *reinterpret_cast<const float4*>(&ek_t[sbase + k0 + 4]);
    float ek[8] = {e0v.x, e0v.y, e0v.z, e0v.w, e1v.x, e1v.y, e1v.z, e1v.w};
    float eq[8];
    #pragma unroll
    for (int g = 0; g < 8; g++)
        eq[g] = eq_t[sbase + q0 + wave * 8 + g];

    // ---- stage tile 0 into Vt[0] (waits only A-regs) ----
    WRITEV(A0, A1, A2, A3, 0);
    LOADS(A0, A1, A2, A3, 2);          // set A now carries tile 2

    // ---- phase 1: w[q][k] = exp(tanh) = e^{1-2z}, z = rcp(u+1), u = eq*ek ----
    #pragma unroll
    for (int g = 0; g < 8; g++) {
        int q = wave * 8 + g;
        float eqv = eq[g];
        bf16x8 wv;
        #pragma unroll
        for (int j = 0; j < 8; j++) {
            float u = eqv * ek[j];
            float z = __builtin_amdgcn_rcpf(u + 1.f);
            float p = __expf(fmaf(z, -2.f, 1.f));
            wv[j] = (__bf16)(u > 0.f ? p : 1.0f);   // masked: exp(-1e-8) ~= 1
        }
        *reinterpret_cast<bf16x8*>(&w[q][k0 ^ ((q & 7) << 3)]) = wv;   // swizzled store
    }
    BAR_LGKM();                        // flushes w + Vt[0]; globals stay in flight

    // ---- phase 2: PV via MFMA + ones-column row-sums; 1 barrier/tile ----
    bf16x8 vones;
    #pragma unroll
    for (int e = 0; e < 8; e++) vones[e] = (__bf16)1.0f;

    f32x4 acc[2][2] = {};
    f32x4 accs[2] = {};

    const int wswz = (lr & 7) << 3;    // per-lane w col swizzle

    #pragma unroll
    for (int t = 0; t < 8; t++) {
        const int buf = t & 1;
        const char* vtr = reinterpret_cast<const char*>(&Vt[buf][0]);
        // prefetch next tile into the other buffer (independent of MFMA reads)
        if (t < 7) {
            if ((t & 1) == 0) WRITEV(B0, B1, B2, B3, buf ^ 1);
            else              WRITEV(A0, A1, A2, A3, buf ^ 1);
        }
        if (t < 5) {
            if ((t & 1) == 0) LOADS(B0, B1, B2, B3, t + 3);
            else              LOADS(A0, A1, A2, A3, t + 3);
        }
        __builtin_amdgcn_s_setprio(1);
        #pragma unroll
        for (int ks = 0; ks < 2; ks++) {
            int cb = (t * 64 + ks * 32 + lg * 8) ^ wswz;
            bf16x8 af0 = *reinterpret_cast<const bf16x8*>(&w[lr][cb]);
            bf16x8 af1 = *reinterpret_cast<const bf16x8*>(&w[16 + lr][cb]);
            #pragma unroll
            for (int n = 0; n < 2; n++) {
                int d    = wd0 + n * 16 + lr;
                int kbk  = ks * 4 + lg;
                int swzd = (d & 7) ^ ((d >> 3) & 7);
                bf16x8 bv = *reinterpret_cast<const bf16x8*>(vtr + d * 128 + ((kbk ^ swzd) << 4));
                acc[0][n] = __builtin_amdgcn_mfma_f32_16x16x32_bf16(af0, bv, acc[0][n], 0, 0, 0);
                acc[1][n] = __builtin_amdgcn_mfma_f32_16x16x32_bf16(af1, bv, acc[1][n], 0, 0, 0);
            }
            accs[0] = __builtin_amdgcn_mfma_f32_16x16x32_bf16(af0, vones, accs[0], 0, 0, 0);
            accs[1] = __builtin_amdgcn_mfma_f32_16x16x32_bf16(af1, vones, accs[1], 0, 0, 0);
        }
        __builtin_amdgcn_s_setprio(0);
        if (t < 7) BAR_LGKM();         // one barrier per tile (dbuf makes it safe)
    }

    // ---- epilogue: rden lane-local (from ones-MFMA), tanh, +residual ----
    #pragma unroll
    for (int qh = 0; qh < 2; qh++) {
        #pragma unroll
        for (int r = 0; r < 4; r++) {
            int ql = qh * 16 + lg * 4 + r;
            float rden = __builtin_amdgcn_rcpf(accs[qh][r]);
            #pragma unroll
            for (int n = 0; n < 2; n++) {
                int d  = wd0 + n * 16 + lr;
                float hv = acc[qh][n][r] * rden;
                float e2 = __expf(2.f * hv);
                float tv = 1.f - 2.f * __builtin_amdgcn_rcpf(e2 + 1.f);   // tanh(hv)
                size_t o = ((size_t)(b * NSEQ + q0 + ql)) * DMODEL + (size_t)h * DHEAD + d;
                float ov = res[qh][r][n] + tv;
                out[o] = ov;
                if (out_bf) out_bf[o] = (__bf16)ov;
            }
        }
    }
    #undef LOADS
    #undef WRITEV
}

extern "C" void kernel_launch(void* const* d_in, const int* in_sizes, int n_in,
                              void* d_out, int out_size, void* d_ws, size_t ws_size,
                              hipStream_t stream) {
    const float* pmask   = (const float*)d_in[0];
    const float* feature = (const float*)d_in[1];
    const float* W       = (const float*)d_in[2];
    const float* Wa      = (const float*)d_in[3];
    float* out = (float*)d_out;
    char* ws = (char*)d_ws;

    __bf16* Abf  = (__bf16*)ws;
    __bf16* Wbf  = (__bf16*)(ws + 12582912);
    __bf16* QKbf = (__bf16*)(ws + 12582912 + 1179648);
    float*  eq   = (float*)(ws + 12582912 + 1179648 + 12582912);
    float*  ek   = eq + MROWS * NHEAD;

    const int featN4 = (MROWS * DMODEL) / 4;
    const int wN4    = (DMODEL * DMODEL) / 4;

    hipLaunchKernelGGL(cvt_bf16_kernel, dim3((wN4 + 255) / 256), dim3(256), 0, stream,
                       W, Wbf, wN4);

    // ---- layer 1 ----
    hipLaunchKernelGGL(cvt_bf16_kernel, dim3((featN4 + 255) / 256), dim3(256), 0, stream,
                       feature, Abf, featN4);
    hipLaunchKernelGGL(gemm_bt, dim3(768), dim3(256), 0, stream,
                       Abf, Wbf, QKbf, Wa, pmask, eq, ek);
    hipLaunchKernelGGL(attn_pv, dim3(1536), dim3(256), 0, stream,
                       QKbf, eq, ek, feature, out, Abf);

    // ---- layer 2 ----
    hipLaunchKernelGGL(gemm_bt, dim3(768), dim3(256), 0, stream,
                       Abf, Wbf, QKbf, Wa, pmask, eq, ek);
    hipLaunchKernelGGL(attn_pv, dim3(1536), dim3(256), 0, stream,
                       QKbf, eq, ek, out, out, (__bf16*)nullptr);
}